// Round 1
// 898.600 us; speedup vs baseline: 1.1972x; 1.1972x over previous
//
#include <hip/hip_runtime.h>
#include <cstdint>
#include <cstddef>

#define H 768
#define NHEAD 12
#define DH 64
#define FFD 3072
#define BATCH 8
#define SEQ 1024
#define NTOK (BATCH*SEQ)   // 8192

typedef __bf16 bf16x8 __attribute__((ext_vector_type(8)));
typedef float  floatx4 __attribute__((ext_vector_type(4)));

#define MFMA_BF16(a,b,c) __builtin_amdgcn_mfma_f32_16x16x32_bf16((a),(b),(c),0,0,0)

// ---------------------------------------------------------------- LayerNorm
// one wave per row of 768 fp32; output bf16
__global__ __launch_bounds__(256) void ln_kernel(const float* __restrict__ x,
                                                 const float* __restrict__ g,
                                                 const float* __restrict__ be,
                                                 __bf16* __restrict__ out) {
    int row  = blockIdx.x * 4 + (threadIdx.x >> 6);
    int lane = threadIdx.x & 63;
    const float* xr = x + (size_t)row * H;
    float v[12];
    float s = 0.f;
#pragma unroll
    for (int i = 0; i < 12; i++) { v[i] = xr[lane + i * 64]; s += v[i]; }
#pragma unroll
    for (int m = 32; m >= 1; m >>= 1) s += __shfl_xor(s, m, 64);
    float mu = s * (1.0f / H);
    float q = 0.f;
#pragma unroll
    for (int i = 0; i < 12; i++) { float d = v[i] - mu; q += d * d; }
#pragma unroll
    for (int m = 32; m >= 1; m >>= 1) q += __shfl_xor(q, m, 64);
    float rstd = rsqrtf(q * (1.0f / H) + 1e-6f);
    __bf16* orow = out + (size_t)row * H;
#pragma unroll
    for (int i = 0; i < 12; i++) {
        int c = lane + i * 64;
        orow[c] = (__bf16)((v[i] - mu) * rstd * g[c] + be[c]);
    }
}

// ------------------------------------------------- weight fp32(K,N) -> bf16 T(N,K)
__global__ __launch_bounds__(256) void wtrans_kernel(const float* __restrict__ W,
                                                     __bf16* __restrict__ T,
                                                     int K, int Nn) {
    __shared__ float tile[32][33];
    int tx = threadIdx.x & 31;
    int ty = threadIdx.x >> 5;            // 0..7
    int n0 = blockIdx.x * 32, k0 = blockIdx.y * 32;
#pragma unroll
    for (int i = 0; i < 32; i += 8)
        tile[ty + i][tx] = W[(size_t)(k0 + ty + i) * Nn + n0 + tx];
    __syncthreads();
#pragma unroll
    for (int i = 0; i < 32; i += 8)
        T[(size_t)(n0 + ty + i) * K + k0 + tx] = (__bf16)tile[tx][ty + i];
}

// ------------------------------------------------- v (8192,768) -> vT (b,h,64,1024)
__global__ __launch_bounds__(256) void vtrans_kernel(const __bf16* __restrict__ v,
                                                     __bf16* __restrict__ vT) {
    __shared__ __bf16 tile[64][65];
    int b = blockIdx.z, h = blockIdx.y, n0 = blockIdx.x * 64;
    int tx = threadIdx.x, ty = threadIdx.y;
#pragma unroll
    for (int r = ty; r < 64; r += 4)
        tile[r][tx] = v[((size_t)b * SEQ + n0 + r) * H + h * DH + tx];
    __syncthreads();
#pragma unroll
    for (int c = ty; c < 64; c += 4)
        vT[(((size_t)b * NHEAD + h) * DH + c) * SEQ + n0 + tx] = tile[tx][c];
}

// ---------------------------------------------------------------- GEMM
// C(M,Nn) = A(M,K)bf16 @ Bt(Nn,K)bf16^T + bias ; optional erf-GELU, fp32 residual
// 128x128 tile, BK=32, 4 waves in 2x2, each wave 64x64 = 4x4 MFMA 16x16x32
template<bool GELU, bool HAS_RES, bool OUT_BF16>
__global__ __launch_bounds__(256) void gemm_kernel(const __bf16* __restrict__ A,
                                                   const __bf16* __restrict__ Bt,
                                                   const float* __restrict__ bias,
                                                   const float* __restrict__ res,
                                                   __bf16* __restrict__ obf,
                                                   float* __restrict__ ofp,
                                                   int Nn, int K) {
    __shared__ __bf16 As[128 * 32];
    __shared__ __bf16 Bs[128 * 32];
    int tid = threadIdx.x;
    int wave = tid >> 6, lane = tid & 63;
    int wr = wave >> 1, wc = wave & 1;
    int l15 = lane & 15, quad = lane >> 4;

    floatx4 acc[4][4];
    floatx4 zero = {0.f, 0.f, 0.f, 0.f};
#pragma unroll
    for (int i = 0; i < 4; i++)
#pragma unroll
        for (int j = 0; j < 4; j++) acc[i][j] = zero;

    int srow = tid >> 1;          // 0..127
    int scol = (tid & 1) * 16;    // 0 / 16
    const __bf16* Ag = A + (size_t)(blockIdx.y * 128 + srow) * K + scol;
    const __bf16* Bg = Bt + (size_t)(blockIdx.x * 128 + srow) * K + scol;
    __bf16* AsW = &As[srow * 32 + scol];
    __bf16* BsW = &Bs[srow * 32 + scol];

    for (int k0 = 0; k0 < K; k0 += 32) {
        *(bf16x8*)(AsW)     = *(const bf16x8*)(Ag + k0);
        *(bf16x8*)(AsW + 8) = *(const bf16x8*)(Ag + k0 + 8);
        *(bf16x8*)(BsW)     = *(const bf16x8*)(Bg + k0);
        *(bf16x8*)(BsW + 8) = *(const bf16x8*)(Bg + k0 + 8);
        __syncthreads();
        bf16x8 af[4], bfv[4];
#pragma unroll
        for (int i = 0; i < 4; i++)
            af[i] = *(const bf16x8*)&As[(wr * 64 + i * 16 + l15) * 32 + quad * 8];
#pragma unroll
        for (int j = 0; j < 4; j++)
            bfv[j] = *(const bf16x8*)&Bs[(wc * 64 + j * 16 + l15) * 32 + quad * 8];
#pragma unroll
        for (int i = 0; i < 4; i++)
#pragma unroll
            for (int j = 0; j < 4; j++)
                acc[i][j] = MFMA_BF16(af[i], bfv[j], acc[i][j]);
        __syncthreads();
    }

#pragma unroll
    for (int i = 0; i < 4; i++) {
        int row = blockIdx.y * 128 + wr * 64 + i * 16 + quad * 4;
#pragma unroll
        for (int j = 0; j < 4; j++) {
            int col = blockIdx.x * 128 + wc * 64 + j * 16 + l15;
            float bsv = bias[col];
#pragma unroll
            for (int r = 0; r < 4; r++) {
                float vv = acc[i][j][r] + bsv;
                if (GELU) vv = 0.5f * vv * (1.0f + erff(vv * 0.70710678118654752f));
                if (HAS_RES) vv += res[(size_t)(row + r) * Nn + col];
                if (OUT_BF16) obf[(size_t)(row + r) * Nn + col] = (__bf16)vv;
                else          ofp[(size_t)(row + r) * Nn + col] = vv;
            }
        }
    }
}

// ---------------------------------------------------------------- Attention
// Per block: 16 query rows of one (b,h). S held entirely in REGISTERS
// (each wave owns 16 column-tiles of 16 -> floatx4 s[16] = 64 VGPR/lane).
// Softmax via in-register reduce + shfl + tiny cross-wave LDS buffer.
// W written fp32 straight from regs (nontemporal). S converted ONCE to a
// 32KB XOR-swizzled bf16 LDS tile that feeds PV ds_read_b128 A-fragments.
// LDS 64KB -> 33KB: 2 -> 4 blocks/CU.

// bf16 element index into Sb with 16B XOR swizzle on the column
__device__ __forceinline__ int sbidx(int row, int col) {
    return row * 1024 + (col ^ ((row & 7) << 3));
}

__global__ __launch_bounds__(256, 4) void attn_kernel(const __bf16* __restrict__ q,
                                                      const __bf16* __restrict__ k,
                                                      const __bf16* __restrict__ vT,
                                                      float* __restrict__ Wout,
                                                      __bf16* __restrict__ ctx) {
    __shared__ __bf16 Sb[16 * 1024];               // 32 KB, swizzled bf16 weights
    __shared__ __align__(16) float red[2][16][4];  // [max/sum][row][wave]
    int tid = threadIdx.x;
    int wave = tid >> 6, lane = tid & 63, l15 = lane & 15, quad = lane >> 4;
    int rt = blockIdx.x, h = blockIdx.y, b = blockIdx.z;
    const size_t qkbase = ((size_t)b * SEQ) * H + h * DH;
    const float scale = 0.03608439182435161f;   // 1/sqrt(768)

    // q fragments (16 rows x 64 k) in regs, shared by all column tiles
    const __bf16* qrow = q + qkbase + (size_t)(rt * 16 + l15) * H;
    bf16x8 qf0 = *(const bf16x8*)(qrow + quad * 8);
    bf16x8 qf1 = *(const bf16x8*)(qrow + 32 + quad * 8);

    // ---- QK^T: wave owns 16 contiguous column tiles; S stays in regs
    floatx4 s[16];
    const __bf16* kbase = k + qkbase;
#pragma unroll
    for (int i = 0; i < 16; i++) {
        int ct = wave * 16 + i;
        const __bf16* krow = kbase + (size_t)(ct * 16 + l15) * H;
        bf16x8 kf0 = *(const bf16x8*)(krow + quad * 8);
        bf16x8 kf1 = *(const bf16x8*)(krow + 32 + quad * 8);
        floatx4 a = {0.f, 0.f, 0.f, 0.f};
        a = MFMA_BF16(qf0, kf0, a);
        a = MFMA_BF16(qf1, kf1, a);
#pragma unroll
        for (int r = 0; r < 4; r++) s[i][r] = a[r] * scale;
    }

    // ---- row max: local over 16 tiles, shfl over 16 lanes, LDS over 4 waves
    float m4[4];
#pragma unroll
    for (int r = 0; r < 4; r++) {
        float m = s[0][r];
#pragma unroll
        for (int i = 1; i < 16; i++) m = fmaxf(m, s[i][r]);
#pragma unroll
        for (int msk = 8; msk >= 1; msk >>= 1) m = fmaxf(m, __shfl_xor(m, msk, 64));
        m4[r] = m;
    }
    if (l15 == 0) {
#pragma unroll
        for (int r = 0; r < 4; r++) red[0][quad * 4 + r][wave] = m4[r];
    }
    __syncthreads();
    float mrow[4];
#pragma unroll
    for (int r = 0; r < 4; r++) {
        float4 rr = *(const float4*)&red[0][quad * 4 + r][0];
        mrow[r] = fmaxf(fmaxf(rr.x, rr.y), fmaxf(rr.z, rr.w));
    }

    // ---- exp + row sum (same reduction path)
    float s4[4] = {0.f, 0.f, 0.f, 0.f};
#pragma unroll
    for (int i = 0; i < 16; i++) {
#pragma unroll
        for (int r = 0; r < 4; r++) {
            float e = __expf(s[i][r] - mrow[r]);
            s[i][r] = e;
            s4[r] += e;
        }
    }
#pragma unroll
    for (int r = 0; r < 4; r++) {
#pragma unroll
        for (int msk = 8; msk >= 1; msk >>= 1) s4[r] += __shfl_xor(s4[r], msk, 64);
    }
    if (l15 == 0) {
#pragma unroll
        for (int r = 0; r < 4; r++) red[1][quad * 4 + r][wave] = s4[r];
    }
    __syncthreads();
    float inv[4];
#pragma unroll
    for (int r = 0; r < 4; r++) {
        float4 rr = *(const float4*)&red[1][quad * 4 + r][0];
        inv[r] = 1.0f / (rr.x + rr.y + rr.z + rr.w);
    }

    // ---- normalize: fp32 W straight to global (nontemporal), bf16 copy to LDS
    size_t wbase = (((size_t)b * NHEAD + h) * SEQ + rt * 16) * SEQ;
#pragma unroll
    for (int i = 0; i < 16; i++) {
        int col = (wave * 16 + i) * 16 + l15;
#pragma unroll
        for (int r = 0; r < 4; r++) {
            float w = s[i][r] * inv[r];
            int row = quad * 4 + r;
            __builtin_nontemporal_store(w, &Wout[wbase + (size_t)row * SEQ + col]);
            Sb[sbidx(row, col)] = (__bf16)w;
        }
    }
    __syncthreads();

    // ---- PV: ctx(16x64) = W(16x1024) @ v(1024x64); wave owns 16 d-cols
    floatx4 acc = {0.f, 0.f, 0.f, 0.f};
    const __bf16* vbase = vT + (((size_t)b * NHEAD + h) * DH + wave * 16 + l15) * SEQ;
#pragma unroll
    for (int c = 0; c < 32; c++) {
        int k0 = c * 32 + quad * 8;
        bf16x8 af = *(const bf16x8*)&Sb[sbidx(l15, k0)];
        bf16x8 bv = *(const bf16x8*)(vbase + k0);
        acc = MFMA_BF16(af, bv, acc);
    }
#pragma unroll
    for (int r = 0; r < 4; r++)
        ctx[((size_t)b * SEQ + rt * 16 + quad * 4 + r) * H + h * DH + wave * 16 + l15] =
            (__bf16)acc[r];
}

// ---------------------------------------------------------------- launch
extern "C" void kernel_launch(void* const* d_in, const int* in_sizes, int n_in,
                              void* d_out, int out_size, void* d_ws, size_t ws_size,
                              hipStream_t stream) {
    const float* x   = (const float*)d_in[0];
    const float* wq  = (const float*)d_in[1];
    const float* bq  = (const float*)d_in[2];
    const float* wk  = (const float*)d_in[3];
    const float* bk  = (const float*)d_in[4];
    const float* wv  = (const float*)d_in[5];
    const float* bv  = (const float*)d_in[6];
    const float* wo  = (const float*)d_in[7];
    const float* bo  = (const float*)d_in[8];
    const float* w1  = (const float*)d_in[9];
    const float* b1  = (const float*)d_in[10];
    const float* w2  = (const float*)d_in[11];
    const float* b2  = (const float*)d_in[12];
    const float* g1  = (const float*)d_in[13];
    const float* be1 = (const float*)d_in[14];
    const float* g2  = (const float*)d_in[15];
    const float* be2 = (const float*)d_in[16];

    char* ws = (char*)d_ws;
    const size_t SZB = (size_t)NTOK * H * 2;           // 12582912
    __bf16* x1b  = (__bf16*)(ws);
    __bf16* qb   = (__bf16*)(ws + SZB);
    __bf16* kb   = (__bf16*)(ws + 2 * SZB);
    __bf16* vb   = (__bf16*)(ws + 3 * SZB);
    __bf16* vTb  = (__bf16*)(ws + 4 * SZB);
    __bf16* ctxb = (__bf16*)(ws + 5 * SZB);
    __bf16* x2b  = (__bf16*)(ws + 6 * SZB);
    __bf16* hb   = (__bf16*)(ws + 7 * SZB);            // 8192*3072*2
    size_t off = 7 * SZB + (size_t)NTOK * FFD * 2;
    float* xattn = (float*)(ws + off); off += (size_t)NTOK * H * 4;
    __bf16* wqT = (__bf16*)(ws + off); off += (size_t)H * H * 2;
    __bf16* wkT = (__bf16*)(ws + off); off += (size_t)H * H * 2;
    __bf16* wvT = (__bf16*)(ws + off); off += (size_t)H * H * 2;
    __bf16* woT = (__bf16*)(ws + off); off += (size_t)H * H * 2;
    __bf16* w1T = (__bf16*)(ws + off); off += (size_t)H * FFD * 2;
    __bf16* w2T = (__bf16*)(ws + off); off += (size_t)FFD * H * 2;

    float* outx = (float*)d_out;
    float* outw = (float*)d_out + (size_t)NTOK * H;

    // weights -> bf16, transposed to (N,K)
    wtrans_kernel<<<dim3(24, 24), 256, 0, stream>>>(wq, wqT, H, H);
    wtrans_kernel<<<dim3(24, 24), 256, 0, stream>>>(wk, wkT, H, H);
    wtrans_kernel<<<dim3(24, 24), 256, 0, stream>>>(wv, wvT, H, H);
    wtrans_kernel<<<dim3(24, 24), 256, 0, stream>>>(wo, woT, H, H);
    wtrans_kernel<<<dim3(96, 24), 256, 0, stream>>>(w1, w1T, H, FFD);
    wtrans_kernel<<<dim3(24, 96), 256, 0, stream>>>(w2, w2T, FFD, H);

    // LN1
    ln_kernel<<<NTOK / 4, 256, 0, stream>>>(x, g1, be1, x1b);

    // QKV projections
    gemm_kernel<false, false, true><<<dim3(H / 128, NTOK / 128), 256, 0, stream>>>(
        x1b, wqT, bq, nullptr, qb, nullptr, H, H);
    gemm_kernel<false, false, true><<<dim3(H / 128, NTOK / 128), 256, 0, stream>>>(
        x1b, wkT, bk, nullptr, kb, nullptr, H, H);
    gemm_kernel<false, false, true><<<dim3(H / 128, NTOK / 128), 256, 0, stream>>>(
        x1b, wvT, bv, nullptr, vb, nullptr, H, H);

    // v -> vT (b,h,d,n)
    vtrans_kernel<<<dim3(16, NHEAD, BATCH), dim3(64, 4), 0, stream>>>(vb, vTb);

    // attention (writes softmax weights to d_out and ctx to ws)
    attn_kernel<<<dim3(64, NHEAD, BATCH), 256, 0, stream>>>(qb, kb, vTb, outw, ctxb);

    // out projection + residual(x) -> xattn fp32
    gemm_kernel<false, true, false><<<dim3(H / 128, NTOK / 128), 256, 0, stream>>>(
        ctxb, woT, bo, x, nullptr, xattn, H, H);

    // LN2
    ln_kernel<<<NTOK / 4, 256, 0, stream>>>(xattn, g2, be2, x2b);

    // FFN1 + exact GELU
    gemm_kernel<true, false, true><<<dim3(FFD / 128, NTOK / 128), 256, 0, stream>>>(
        x2b, w1T, b1, nullptr, hb, nullptr, FFD, H);

    // FFN2 + residual(xattn) -> d_out[0:6291456]
    gemm_kernel<false, true, false><<<dim3(H / 128, NTOK / 128), 256, 0, stream>>>(
        hb, w2T, b2, xattn, nullptr, outx, H, FFD);
}

// Round 2
// 864.589 us; speedup vs baseline: 1.2443x; 1.0393x over previous
//
#include <hip/hip_runtime.h>
#include <cstdint>
#include <cstddef>

#define H 768
#define NHEAD 12
#define DH 64
#define FFD 3072
#define BATCH 8
#define SEQ 1024
#define NTOK (BATCH*SEQ)   // 8192
#define QKVS 2304          // fused qkv row stride

typedef __bf16 bf16x8 __attribute__((ext_vector_type(8)));
typedef float  floatx4 __attribute__((ext_vector_type(4)));

#define MFMA_BF16(a,b,c) __builtin_amdgcn_mfma_f32_16x16x32_bf16((a),(b),(c),0,0,0)

// async global->LDS, 16B per lane; dest must be wave-uniform base (lane*16 auto)
__device__ __forceinline__ void gload16(const void* g, void* l) {
    __builtin_amdgcn_global_load_lds((const __attribute__((address_space(1))) void*)g,
                                     (__attribute__((address_space(3))) void*)l,
                                     16, 0, 0);
}

// ---------------------------------------------------------------- LayerNorm
// one wave per row of 768 fp32; output bf16
__global__ __launch_bounds__(256) void ln_kernel(const float* __restrict__ x,
                                                 const float* __restrict__ g,
                                                 const float* __restrict__ be,
                                                 __bf16* __restrict__ out) {
    int row  = blockIdx.x * 4 + (threadIdx.x >> 6);
    int lane = threadIdx.x & 63;
    const float* xr = x + (size_t)row * H;
    float v[12];
    float s = 0.f;
#pragma unroll
    for (int i = 0; i < 12; i++) { v[i] = xr[lane + i * 64]; s += v[i]; }
#pragma unroll
    for (int m = 32; m >= 1; m >>= 1) s += __shfl_xor(s, m, 64);
    float mu = s * (1.0f / H);
    float q = 0.f;
#pragma unroll
    for (int i = 0; i < 12; i++) { float d = v[i] - mu; q += d * d; }
#pragma unroll
    for (int m = 32; m >= 1; m >>= 1) q += __shfl_xor(q, m, 64);
    float rstd = rsqrtf(q * (1.0f / H) + 1e-6f);
    __bf16* orow = out + (size_t)row * H;
#pragma unroll
    for (int i = 0; i < 12; i++) {
        int c = lane + i * 64;
        orow[c] = (__bf16)((v[i] - mu) * rstd * g[c] + be[c]);
    }
}

// ------------------------------------------------- weight fp32(K,N) -> bf16 T(N,K)
__global__ __launch_bounds__(256) void wtrans_kernel(const float* __restrict__ W,
                                                     __bf16* __restrict__ T,
                                                     int K, int Nn) {
    __shared__ float tile[32][33];
    int tx = threadIdx.x & 31;
    int ty = threadIdx.x >> 5;            // 0..7
    int n0 = blockIdx.x * 32, k0 = blockIdx.y * 32;
#pragma unroll
    for (int i = 0; i < 32; i += 8)
        tile[ty + i][tx] = W[(size_t)(k0 + ty + i) * Nn + n0 + tx];
    __syncthreads();
#pragma unroll
    for (int i = 0; i < 32; i += 8)
        T[(size_t)(n0 + ty + i) * K + k0 + tx] = (__bf16)tile[tx][ty + i];
}

// ------------------------------------------------- bias concat bq|bk|bv -> 2304
__global__ __launch_bounds__(256) void bcat_kernel(const float* __restrict__ bq,
                                                   const float* __restrict__ bk,
                                                   const float* __restrict__ bv,
                                                   float* __restrict__ o) {
    int i = blockIdx.x * 256 + threadIdx.x;
    if (i >= 3 * H) return;
    if (i < H) o[i] = bq[i];
    else if (i < 2 * H) o[i] = bk[i - H];
    else o[i] = bv[i - 2 * H];
}

// --------------------------------- v (from qkv, stride 2304) -> vT (b,h,64,1024)
__global__ __launch_bounds__(256) void vtrans_kernel(const __bf16* __restrict__ qkv,
                                                     __bf16* __restrict__ vT) {
    __shared__ __bf16 tile[64][65];
    int b = blockIdx.z, h = blockIdx.y, n0 = blockIdx.x * 64;
    int tx = threadIdx.x, ty = threadIdx.y;
#pragma unroll
    for (int r = ty; r < 64; r += 4)
        tile[r][tx] = qkv[((size_t)b * SEQ + n0 + r) * QKVS + 2 * H + h * DH + tx];
    __syncthreads();
#pragma unroll
    for (int c = ty; c < 64; c += 4)
        vT[(((size_t)b * NHEAD + h) * DH + c) * SEQ + n0 + tx] = tile[tx][c];
}

// ---------------------------------------------------------------- GEMM
// C(M,Nn) = A(M,K)bf16 @ Bt(Nn,K)bf16^T + bias ; optional erf-GELU, fp32 residual
// 128x128 tile, BK=32, 4 waves 2x2, each wave 64x64 = 4x4 MFMA 16x16x32.
// Staging via global_load_lds width=16: tile = 8 chunks of 1024B, wave w
// issues chunks 2w,2w+1; lane l covers row c*16+l/4, col (l&3)*8 (linear LDS).
template<bool GELU, bool HAS_RES, bool OUT_BF16>
__global__ __launch_bounds__(256) void gemm_kernel(const __bf16* __restrict__ A,
                                                   const __bf16* __restrict__ Bt,
                                                   const float* __restrict__ bias,
                                                   const float* __restrict__ res,
                                                   __bf16* __restrict__ obf,
                                                   float* __restrict__ ofp,
                                                   int Nn, int K) {
    __shared__ __bf16 As[128 * 32];
    __shared__ __bf16 Bs[128 * 32];
    int tid = threadIdx.x;
    int wave = tid >> 6, lane = tid & 63;
    int wr = wave >> 1, wc = wave & 1;
    int l15 = lane & 15, quad = lane >> 4;

    floatx4 acc[4][4];
    floatx4 zero = {0.f, 0.f, 0.f, 0.f};
#pragma unroll
    for (int i = 0; i < 4; i++)
#pragma unroll
        for (int j = 0; j < 4; j++) acc[i][j] = zero;

    int c0 = wave * 2, c1 = c0 + 1;
    int lr = lane >> 2, lc = (lane & 3) * 8;
    const __bf16* Ag0 = A + (size_t)(blockIdx.y * 128 + c0 * 16 + lr) * K + lc;
    const __bf16* Ag1 = A + (size_t)(blockIdx.y * 128 + c1 * 16 + lr) * K + lc;
    const __bf16* Bg0 = Bt + (size_t)(blockIdx.x * 128 + c0 * 16 + lr) * K + lc;
    const __bf16* Bg1 = Bt + (size_t)(blockIdx.x * 128 + c1 * 16 + lr) * K + lc;
    __bf16* AsD0 = &As[c0 * 512];
    __bf16* AsD1 = &As[c1 * 512];
    __bf16* BsD0 = &Bs[c0 * 512];
    __bf16* BsD1 = &Bs[c1 * 512];

    for (int k0 = 0; k0 < K; k0 += 32) {
        gload16(Ag0 + k0, AsD0);
        gload16(Ag1 + k0, AsD1);
        gload16(Bg0 + k0, BsD0);
        gload16(Bg1 + k0, BsD1);
        __syncthreads();              // compiler drains vmcnt before s_barrier
        bf16x8 af[4], bfv[4];
#pragma unroll
        for (int i = 0; i < 4; i++)
            af[i] = *(const bf16x8*)&As[(wr * 64 + i * 16 + l15) * 32 + quad * 8];
#pragma unroll
        for (int j = 0; j < 4; j++)
            bfv[j] = *(const bf16x8*)&Bs[(wc * 64 + j * 16 + l15) * 32 + quad * 8];
#pragma unroll
        for (int i = 0; i < 4; i++)
#pragma unroll
            for (int j = 0; j < 4; j++)
                acc[i][j] = MFMA_BF16(af[i], bfv[j], acc[i][j]);
        __syncthreads();
    }

#pragma unroll
    for (int i = 0; i < 4; i++) {
        int row = blockIdx.y * 128 + wr * 64 + i * 16 + quad * 4;
#pragma unroll
        for (int j = 0; j < 4; j++) {
            int col = blockIdx.x * 128 + wc * 64 + j * 16 + l15;
            float bsv = bias[col];
#pragma unroll
            for (int r = 0; r < 4; r++) {
                float vv = acc[i][j][r] + bsv;
                if (GELU) vv = 0.5f * vv * (1.0f + erff(vv * 0.70710678118654752f));
                if (HAS_RES) vv += res[(size_t)(row + r) * Nn + col];
                if (OUT_BF16) obf[(size_t)(row + r) * Nn + col] = (__bf16)vv;
                else          ofp[(size_t)(row + r) * Nn + col] = vv;
            }
        }
    }
}

// ---------------------------------------------------------------- Attention
// Per block: 16 query rows of one (b,h). S held entirely in REGISTERS.
// q/k read from fused qkv buffer at row stride 2304 (q at +0, k at +768).
__device__ __forceinline__ int sbidx(int row, int col) {
    return row * 1024 + (col ^ ((row & 7) << 3));
}

__global__ __launch_bounds__(256, 4) void attn_kernel(const __bf16* __restrict__ qkv,
                                                      const __bf16* __restrict__ vT,
                                                      float* __restrict__ Wout,
                                                      __bf16* __restrict__ ctx) {
    __shared__ __bf16 Sb[16 * 1024];               // 32 KB, swizzled bf16 weights
    __shared__ __align__(16) float red[2][16][4];  // [max/sum][row][wave]
    int tid = threadIdx.x;
    int wave = tid >> 6, lane = tid & 63, l15 = lane & 15, quad = lane >> 4;
    int rt = blockIdx.x, h = blockIdx.y, b = blockIdx.z;
    const size_t tokbase = (size_t)b * SEQ * QKVS + h * DH;
    const float scale = 0.03608439182435161f;   // 1/sqrt(768)

    // q fragments (16 rows x 64 k) in regs, shared by all column tiles
    const __bf16* qrow = qkv + tokbase + (size_t)(rt * 16 + l15) * QKVS;
    bf16x8 qf0 = *(const bf16x8*)(qrow + quad * 8);
    bf16x8 qf1 = *(const bf16x8*)(qrow + 32 + quad * 8);

    // ---- QK^T: wave owns 16 contiguous column tiles; S stays in regs
    floatx4 s[16];
    const __bf16* kbase = qkv + tokbase + H;       // k at +768 within row
#pragma unroll
    for (int i = 0; i < 16; i++) {
        int ct = wave * 16 + i;
        const __bf16* krow = kbase + (size_t)(ct * 16 + l15) * QKVS;
        bf16x8 kf0 = *(const bf16x8*)(krow + quad * 8);
        bf16x8 kf1 = *(const bf16x8*)(krow + 32 + quad * 8);
        floatx4 a = {0.f, 0.f, 0.f, 0.f};
        a = MFMA_BF16(qf0, kf0, a);
        a = MFMA_BF16(qf1, kf1, a);
#pragma unroll
        for (int r = 0; r < 4; r++) s[i][r] = a[r] * scale;
    }

    // ---- row max: local over 16 tiles, shfl over 16 lanes, LDS over 4 waves
    float m4[4];
#pragma unroll
    for (int r = 0; r < 4; r++) {
        float m = s[0][r];
#pragma unroll
        for (int i = 1; i < 16; i++) m = fmaxf(m, s[i][r]);
#pragma unroll
        for (int msk = 8; msk >= 1; msk >>= 1) m = fmaxf(m, __shfl_xor(m, msk, 64));
        m4[r] = m;
    }
    if (l15 == 0) {
#pragma unroll
        for (int r = 0; r < 4; r++) red[0][quad * 4 + r][wave] = m4[r];
    }
    __syncthreads();
    float mrow[4];
#pragma unroll
    for (int r = 0; r < 4; r++) {
        float4 rr = *(const float4*)&red[0][quad * 4 + r][0];
        mrow[r] = fmaxf(fmaxf(rr.x, rr.y), fmaxf(rr.z, rr.w));
    }

    // ---- exp + row sum (same reduction path)
    float s4[4] = {0.f, 0.f, 0.f, 0.f};
#pragma unroll
    for (int i = 0; i < 16; i++) {
#pragma unroll
        for (int r = 0; r < 4; r++) {
            float e = __expf(s[i][r] - mrow[r]);
            s[i][r] = e;
            s4[r] += e;
        }
    }
#pragma unroll
    for (int r = 0; r < 4; r++) {
#pragma unroll
        for (int msk = 8; msk >= 1; msk >>= 1) s4[r] += __shfl_xor(s4[r], msk, 64);
    }
    if (l15 == 0) {
#pragma unroll
        for (int r = 0; r < 4; r++) red[1][quad * 4 + r][wave] = s4[r];
    }
    __syncthreads();
    float inv[4];
#pragma unroll
    for (int r = 0; r < 4; r++) {
        float4 rr = *(const float4*)&red[1][quad * 4 + r][0];
        inv[r] = 1.0f / (rr.x + rr.y + rr.z + rr.w);
    }

    // ---- normalize: fp32 W straight to global (nontemporal), bf16 copy to LDS
    size_t wbase = (((size_t)b * NHEAD + h) * SEQ + rt * 16) * SEQ;
#pragma unroll
    for (int i = 0; i < 16; i++) {
        int col = (wave * 16 + i) * 16 + l15;
#pragma unroll
        for (int r = 0; r < 4; r++) {
            float w = s[i][r] * inv[r];
            int row = quad * 4 + r;
            __builtin_nontemporal_store(w, &Wout[wbase + (size_t)row * SEQ + col]);
            Sb[sbidx(row, col)] = (__bf16)w;
        }
    }
    __syncthreads();

    // ---- PV: ctx(16x64) = W(16x1024) @ v(1024x64); wave owns 16 d-cols
    floatx4 acc = {0.f, 0.f, 0.f, 0.f};
    const __bf16* vbase = vT + (((size_t)b * NHEAD + h) * DH + wave * 16 + l15) * SEQ;
#pragma unroll
    for (int c = 0; c < 32; c++) {
        int k0 = c * 32 + quad * 8;
        bf16x8 af = *(const bf16x8*)&Sb[sbidx(l15, k0)];
        bf16x8 bv = *(const bf16x8*)(vbase + k0);
        acc = MFMA_BF16(af, bv, acc);
    }
#pragma unroll
    for (int r = 0; r < 4; r++)
        ctx[((size_t)b * SEQ + rt * 16 + quad * 4 + r) * H + h * DH + wave * 16 + l15] =
            (__bf16)acc[r];
}

// ---------------------------------------------------------------- launch
extern "C" void kernel_launch(void* const* d_in, const int* in_sizes, int n_in,
                              void* d_out, int out_size, void* d_ws, size_t ws_size,
                              hipStream_t stream) {
    const float* x   = (const float*)d_in[0];
    const float* wq  = (const float*)d_in[1];
    const float* bq  = (const float*)d_in[2];
    const float* wk  = (const float*)d_in[3];
    const float* bk  = (const float*)d_in[4];
    const float* wv  = (const float*)d_in[5];
    const float* bv  = (const float*)d_in[6];
    const float* wo  = (const float*)d_in[7];
    const float* bo  = (const float*)d_in[8];
    const float* w1  = (const float*)d_in[9];
    const float* b1  = (const float*)d_in[10];
    const float* w2  = (const float*)d_in[11];
    const float* b2  = (const float*)d_in[12];
    const float* g1  = (const float*)d_in[13];
    const float* be1 = (const float*)d_in[14];
    const float* g2  = (const float*)d_in[15];
    const float* be2 = (const float*)d_in[16];

    char* ws = (char*)d_ws;
    const size_t SZB = (size_t)NTOK * H * 2;           // 12582912
    __bf16* x1b  = (__bf16*)(ws);
    __bf16* qkvb = (__bf16*)(ws + SZB);                // (8192, 2304) spans 3*SZB
    __bf16* vTb  = (__bf16*)(ws + 4 * SZB);
    __bf16* ctxb = (__bf16*)(ws + 5 * SZB);
    __bf16* x2b  = (__bf16*)(ws + 6 * SZB);
    __bf16* hb   = (__bf16*)(ws + 7 * SZB);            // 8192*3072*2
    size_t off = 7 * SZB + (size_t)NTOK * FFD * 2;
    float* xattn = (float*)(ws + off); off += (size_t)NTOK * H * 4;
    __bf16* wqkvT = (__bf16*)(ws + off); off += (size_t)3 * H * H * 2;  // (2304,768)
    __bf16* woT  = (__bf16*)(ws + off); off += (size_t)H * H * 2;
    __bf16* w1T  = (__bf16*)(ws + off); off += (size_t)H * FFD * 2;
    __bf16* w2T  = (__bf16*)(ws + off); off += (size_t)FFD * H * 2;
    float* bqkv  = (float*)(ws + off); off += (size_t)3 * H * 4;

    float* outx = (float*)d_out;
    float* outw = (float*)d_out + (size_t)NTOK * H;

    // weights -> bf16, transposed to (N,K); q/k/v stacked into one (2304,768)
    wtrans_kernel<<<dim3(24, 24), 256, 0, stream>>>(wq, wqkvT, H, H);
    wtrans_kernel<<<dim3(24, 24), 256, 0, stream>>>(wk, wqkvT + (size_t)H * H, H, H);
    wtrans_kernel<<<dim3(24, 24), 256, 0, stream>>>(wv, wqkvT + (size_t)2 * H * H, H, H);
    wtrans_kernel<<<dim3(24, 24), 256, 0, stream>>>(wo, woT, H, H);
    wtrans_kernel<<<dim3(96, 24), 256, 0, stream>>>(w1, w1T, H, FFD);
    wtrans_kernel<<<dim3(24, 96), 256, 0, stream>>>(w2, w2T, FFD, H);
    bcat_kernel<<<9, 256, 0, stream>>>(bq, bk, bv, bqkv);

    // LN1
    ln_kernel<<<NTOK / 4, 256, 0, stream>>>(x, g1, be1, x1b);

    // fused QKV projection: (8192,768) @ (2304,768)^T -> (8192,2304)
    gemm_kernel<false, false, true><<<dim3(QKVS / 128, NTOK / 128), 256, 0, stream>>>(
        x1b, wqkvT, bqkv, nullptr, qkvb, nullptr, QKVS, H);

    // v -> vT (b,h,d,n)
    vtrans_kernel<<<dim3(16, NHEAD, BATCH), dim3(64, 4), 0, stream>>>(qkvb, vTb);

    // attention (writes softmax weights to d_out and ctx to ws)
    attn_kernel<<<dim3(64, NHEAD, BATCH), 256, 0, stream>>>(qkvb, vTb, outw, ctxb);

    // out projection + residual(x) -> xattn fp32
    gemm_kernel<false, true, false><<<dim3(H / 128, NTOK / 128), 256, 0, stream>>>(
        ctxb, woT, bo, x, nullptr, xattn, H, H);

    // LN2
    ln_kernel<<<NTOK / 4, 256, 0, stream>>>(xattn, g2, be2, x2b);

    // FFN1 + exact GELU
    gemm_kernel<true, false, true><<<dim3(FFD / 128, NTOK / 128), 256, 0, stream>>>(
        x2b, w1T, b1, nullptr, hb, nullptr, FFD, H);

    // FFN2 + residual(xattn) -> d_out[0:6291456]
    gemm_kernel<false, true, false><<<dim3(H / 128, NTOK / 128), 256, 0, stream>>>(
        hb, w2T, b2, xattn, nullptr, outx, H, FFD);
}

// Round 3
// 851.314 us; speedup vs baseline: 1.2637x; 1.0156x over previous
//
#include <hip/hip_runtime.h>
#include <cstdint>
#include <cstddef>

#define H 768
#define NHEAD 12
#define DH 64
#define FFD 3072
#define BATCH 8
#define SEQ 1024
#define NTOK (BATCH*SEQ)   // 8192
#define QKVS 2304          // fused qkv row stride

typedef __bf16 bf16x8 __attribute__((ext_vector_type(8)));
typedef float  floatx4 __attribute__((ext_vector_type(4)));

#define MFMA_BF16(a,b,c) __builtin_amdgcn_mfma_f32_16x16x32_bf16((a),(b),(c),0,0,0)

// async global->LDS, 16B per lane; dest must be wave-uniform base (lane*16 auto)
__device__ __forceinline__ void gload16(const void* g, void* l) {
    __builtin_amdgcn_global_load_lds((const __attribute__((address_space(1))) void*)g,
                                     (__attribute__((address_space(3))) void*)l,
                                     16, 0, 0);
}

// exact-GELU via A&S 7.1.26 erf (abs err <= 1.5e-7, ~1000x below bf16 noise)
__device__ __forceinline__ float gelu_erf(float x) {
    float z = fabsf(x) * 0.70710678118654752f;
    float t = __builtin_amdgcn_rcpf(1.0f + 0.3275911f * z);
    float poly = t * (0.254829592f +
               t * (-0.284496736f +
               t * (1.421413741f +
               t * (-1.453152027f +
               t * 1.061405429f))));
    float e = __expf(-z * z);
    float erfv = 1.0f - poly * e;
    erfv = copysignf(erfv, x);
    return 0.5f * x * (1.0f + erfv);
}

// ---------------------------------------------------------------- fused prologue
// blocks [0,6912): weight fp32(K,N) -> bf16 T(N,K) in 32x32 tiles
//   [0,576) wq  [576,1152) wk  [1152,1728) wv  -> wqkvT (stacked)
//   [1728,2304) wo -> woT
//   [2304,4608) w1 (gx=96) -> w1T
//   [4608,6912) w2 (gx=24, K=3072) -> w2T
// blocks [6912,6921): bias concat bq|bk|bv -> bqkv (2304 floats)
// blocks [6921,8969): LayerNorm1, 4 rows/block
__global__ __launch_bounds__(256) void prep_kernel(
    const float* __restrict__ wq, const float* __restrict__ wk,
    const float* __restrict__ wv, const float* __restrict__ wo,
    const float* __restrict__ w1, const float* __restrict__ w2,
    const float* __restrict__ bq, const float* __restrict__ bk,
    const float* __restrict__ bv,
    __bf16* __restrict__ wqkvT, __bf16* __restrict__ woT,
    __bf16* __restrict__ w1T, __bf16* __restrict__ w2T,
    float* __restrict__ bqkv,
    const float* __restrict__ x, const float* __restrict__ g1,
    const float* __restrict__ be1, __bf16* __restrict__ x1b) {
    __shared__ float tile[32][33];
    int bid = blockIdx.x;
    int tid = threadIdx.x;
    if (bid < 6912) {
        const float* W; __bf16* T; int Kd, Nn, bx, by;
        if (bid < 1728) {
            int part = bid / 576;          // 0 wq, 1 wk, 2 wv
            int rem = bid - part * 576;
            W = part == 0 ? wq : (part == 1 ? wk : wv);
            T = wqkvT + (size_t)part * H * H;
            Kd = H; Nn = H; bx = rem % 24; by = rem / 24;
        } else if (bid < 2304) {
            int rem = bid - 1728;
            W = wo; T = woT; Kd = H; Nn = H; bx = rem % 24; by = rem / 24;
        } else if (bid < 4608) {
            int rem = bid - 2304;
            W = w1; T = w1T; Kd = H; Nn = FFD; bx = rem % 96; by = rem / 96;
        } else {
            int rem = bid - 4608;
            W = w2; T = w2T; Kd = FFD; Nn = H; bx = rem % 24; by = rem / 24;
        }
        int tx = tid & 31, ty = tid >> 5;
        int n0 = bx * 32, k0 = by * 32;
#pragma unroll
        for (int i = 0; i < 32; i += 8)
            tile[ty + i][tx] = W[(size_t)(k0 + ty + i) * Nn + n0 + tx];
        __syncthreads();
#pragma unroll
        for (int i = 0; i < 32; i += 8)
            T[(size_t)(n0 + ty + i) * Kd + k0 + tx] = (__bf16)tile[tx][ty + i];
    } else if (bid < 6921) {
        int i = (bid - 6912) * 256 + tid;   // 2304 exact
        float v = i < H ? bq[i] : (i < 2 * H ? bk[i - H] : bv[i - 2 * H]);
        bqkv[i] = v;
    } else {
        int row  = (bid - 6921) * 4 + (tid >> 6);
        int lane = tid & 63;
        const float* xr = x + (size_t)row * H;
        float v[12];
        float s = 0.f;
#pragma unroll
        for (int i = 0; i < 12; i++) { v[i] = xr[lane + i * 64]; s += v[i]; }
#pragma unroll
        for (int m = 32; m >= 1; m >>= 1) s += __shfl_xor(s, m, 64);
        float mu = s * (1.0f / H);
        float q = 0.f;
#pragma unroll
        for (int i = 0; i < 12; i++) { float d = v[i] - mu; q += d * d; }
#pragma unroll
        for (int m = 32; m >= 1; m >>= 1) q += __shfl_xor(q, m, 64);
        float rstd = rsqrtf(q * (1.0f / H) + 1e-6f);
        __bf16* orow = x1b + (size_t)row * H;
#pragma unroll
        for (int i = 0; i < 12; i++) {
            int c = lane + i * 64;
            orow[c] = (__bf16)((v[i] - mu) * rstd * g1[c] + be1[c]);
        }
    }
}

// ---------------------------------------------------------------- LayerNorm (LN2)
__global__ __launch_bounds__(256) void ln_kernel(const float* __restrict__ x,
                                                 const float* __restrict__ g,
                                                 const float* __restrict__ be,
                                                 __bf16* __restrict__ out) {
    int row  = blockIdx.x * 4 + (threadIdx.x >> 6);
    int lane = threadIdx.x & 63;
    const float* xr = x + (size_t)row * H;
    float v[12];
    float s = 0.f;
#pragma unroll
    for (int i = 0; i < 12; i++) { v[i] = xr[lane + i * 64]; s += v[i]; }
#pragma unroll
    for (int m = 32; m >= 1; m >>= 1) s += __shfl_xor(s, m, 64);
    float mu = s * (1.0f / H);
    float q = 0.f;
#pragma unroll
    for (int i = 0; i < 12; i++) { float d = v[i] - mu; q += d * d; }
#pragma unroll
    for (int m = 32; m >= 1; m >>= 1) q += __shfl_xor(q, m, 64);
    float rstd = rsqrtf(q * (1.0f / H) + 1e-6f);
    __bf16* orow = out + (size_t)row * H;
#pragma unroll
    for (int i = 0; i < 12; i++) {
        int c = lane + i * 64;
        orow[c] = (__bf16)((v[i] - mu) * rstd * g[c] + be[c]);
    }
}

// --------------------------------- v (from qkv, stride 2304) -> vT (b,h,64,1024)
__global__ __launch_bounds__(256) void vtrans_kernel(const __bf16* __restrict__ qkv,
                                                     __bf16* __restrict__ vT) {
    __shared__ __bf16 tile[64][65];
    int b = blockIdx.z, h = blockIdx.y, n0 = blockIdx.x * 64;
    int tx = threadIdx.x, ty = threadIdx.y;
#pragma unroll
    for (int r = ty; r < 64; r += 4)
        tile[r][tx] = qkv[((size_t)b * SEQ + n0 + r) * QKVS + 2 * H + h * DH + tx];
    __syncthreads();
#pragma unroll
    for (int c = ty; c < 64; c += 4)
        vT[(((size_t)b * NHEAD + h) * DH + c) * SEQ + n0 + tx] = tile[tx][c];
}

// ---------------------------------------------------------------- GEMM
// C(M,Nn) = A(M,K)bf16 @ Bt(Nn,K)bf16^T + bias ; optional erf-GELU, fp32 residual
// 128x128 tile, BK=32, 4 waves 2x2, each wave 64x64 = 4x4 MFMA 16x16x32.
// Staging via global_load_lds width=16 (m97 structure).
template<bool GELU, bool HAS_RES, bool OUT_BF16>
__global__ __launch_bounds__(256) void gemm_kernel(const __bf16* __restrict__ A,
                                                   const __bf16* __restrict__ Bt,
                                                   const float* __restrict__ bias,
                                                   const float* __restrict__ res,
                                                   __bf16* __restrict__ obf,
                                                   float* __restrict__ ofp,
                                                   int Nn, int K) {
    __shared__ __bf16 As[128 * 32];
    __shared__ __bf16 Bs[128 * 32];
    int tid = threadIdx.x;
    int wave = tid >> 6, lane = tid & 63;
    int wr = wave >> 1, wc = wave & 1;
    int l15 = lane & 15, quad = lane >> 4;

    floatx4 acc[4][4];
    floatx4 zero = {0.f, 0.f, 0.f, 0.f};
#pragma unroll
    for (int i = 0; i < 4; i++)
#pragma unroll
        for (int j = 0; j < 4; j++) acc[i][j] = zero;

    int c0 = wave * 2, c1 = c0 + 1;
    int lr = lane >> 2, lc = (lane & 3) * 8;
    const __bf16* Ag0 = A + (size_t)(blockIdx.y * 128 + c0 * 16 + lr) * K + lc;
    const __bf16* Ag1 = A + (size_t)(blockIdx.y * 128 + c1 * 16 + lr) * K + lc;
    const __bf16* Bg0 = Bt + (size_t)(blockIdx.x * 128 + c0 * 16 + lr) * K + lc;
    const __bf16* Bg1 = Bt + (size_t)(blockIdx.x * 128 + c1 * 16 + lr) * K + lc;
    __bf16* AsD0 = &As[c0 * 512];
    __bf16* AsD1 = &As[c1 * 512];
    __bf16* BsD0 = &Bs[c0 * 512];
    __bf16* BsD1 = &Bs[c1 * 512];

    for (int k0 = 0; k0 < K; k0 += 32) {
        gload16(Ag0 + k0, AsD0);
        gload16(Ag1 + k0, AsD1);
        gload16(Bg0 + k0, BsD0);
        gload16(Bg1 + k0, BsD1);
        __syncthreads();              // compiler drains vmcnt before s_barrier
        bf16x8 af[4], bfv[4];
#pragma unroll
        for (int i = 0; i < 4; i++)
            af[i] = *(const bf16x8*)&As[(wr * 64 + i * 16 + l15) * 32 + quad * 8];
#pragma unroll
        for (int j = 0; j < 4; j++)
            bfv[j] = *(const bf16x8*)&Bs[(wc * 64 + j * 16 + l15) * 32 + quad * 8];
#pragma unroll
        for (int i = 0; i < 4; i++)
#pragma unroll
            for (int j = 0; j < 4; j++)
                acc[i][j] = MFMA_BF16(af[i], bfv[j], acc[i][j]);
        __syncthreads();
    }

#pragma unroll
    for (int i = 0; i < 4; i++) {
        int row = blockIdx.y * 128 + wr * 64 + i * 16 + quad * 4;
#pragma unroll
        for (int j = 0; j < 4; j++) {
            int col = blockIdx.x * 128 + wc * 64 + j * 16 + l15;
            float bsv = bias[col];
#pragma unroll
            for (int r = 0; r < 4; r++) {
                float vv = acc[i][j][r] + bsv;
                if (GELU) vv = gelu_erf(vv);
                if (HAS_RES) vv += res[(size_t)(row + r) * Nn + col];
                if (OUT_BF16) obf[(size_t)(row + r) * Nn + col] = (__bf16)vv;
                else          ofp[(size_t)(row + r) * Nn + col] = vv;
            }
        }
    }
}

// ---------------------------------------------------------------- Attention
// Per block: 16 query rows of one (b,h). S held entirely in REGISTERS.
// XCD-locality remap: all 64 rt-blocks of one (b,h) land on ONE XCD so the
// 256KB K/V slice stays resident in that XCD's private L2 (dispatch is
// round-robin on linear block id; XCD = linear & 7).
__device__ __forceinline__ int sbidx(int row, int col) {
    return row * 1024 + (col ^ ((row & 7) << 3));
}

__global__ __launch_bounds__(256, 4) void attn_kernel(const __bf16* __restrict__ qkv,
                                                      const __bf16* __restrict__ vT,
                                                      float* __restrict__ Wout,
                                                      __bf16* __restrict__ ctx) {
    __shared__ __bf16 Sb[16 * 1024];               // 32 KB, swizzled bf16 weights
    __shared__ __align__(16) float red[2][16][4];  // [max/sum][row][wave]
    int tid = threadIdx.x;
    int wave = tid >> 6, lane = tid & 63, l15 = lane & 15, quad = lane >> 4;

    // bijective remap: XCD (linear&7) owns whole (b,h) groups
    int linear = blockIdx.x + 64 * (blockIdx.y + 12 * blockIdx.z);
    int xcd = linear & 7;
    int j   = linear >> 3;                 // 0..767
    int bh  = xcd + 8 * (j >> 6);          // 0..95
    int rt  = j & 63;
    int h = bh % NHEAD, b = bh / NHEAD;

    const size_t tokbase = (size_t)b * SEQ * QKVS + h * DH;
    const float scale = 0.03608439182435161f;   // 1/sqrt(768)

    // q fragments (16 rows x 64 k) in regs, shared by all column tiles
    const __bf16* qrow = qkv + tokbase + (size_t)(rt * 16 + l15) * QKVS;
    bf16x8 qf0 = *(const bf16x8*)(qrow + quad * 8);
    bf16x8 qf1 = *(const bf16x8*)(qrow + 32 + quad * 8);

    // ---- QK^T: wave owns 16 contiguous column tiles; S stays in regs
    floatx4 s[16];
    const __bf16* kbase = qkv + tokbase + H;       // k at +768 within row
#pragma unroll
    for (int i = 0; i < 16; i++) {
        int ct = wave * 16 + i;
        const __bf16* krow = kbase + (size_t)(ct * 16 + l15) * QKVS;
        bf16x8 kf0 = *(const bf16x8*)(krow + quad * 8);
        bf16x8 kf1 = *(const bf16x8*)(krow + 32 + quad * 8);
        floatx4 a = {0.f, 0.f, 0.f, 0.f};
        a = MFMA_BF16(qf0, kf0, a);
        a = MFMA_BF16(qf1, kf1, a);
#pragma unroll
        for (int r = 0; r < 4; r++) s[i][r] = a[r] * scale;
    }

    // ---- row max: local over 16 tiles, shfl over 16 lanes, LDS over 4 waves
    float m4[4];
#pragma unroll
    for (int r = 0; r < 4; r++) {
        float m = s[0][r];
#pragma unroll
        for (int i = 1; i < 16; i++) m = fmaxf(m, s[i][r]);
#pragma unroll
        for (int msk = 8; msk >= 1; msk >>= 1) m = fmaxf(m, __shfl_xor(m, msk, 64));
        m4[r] = m;
    }
    if (l15 == 0) {
#pragma unroll
        for (int r = 0; r < 4; r++) red[0][quad * 4 + r][wave] = m4[r];
    }
    __syncthreads();
    float mrow[4];
#pragma unroll
    for (int r = 0; r < 4; r++) {
        float4 rr = *(const float4*)&red[0][quad * 4 + r][0];
        mrow[r] = fmaxf(fmaxf(rr.x, rr.y), fmaxf(rr.z, rr.w));
    }

    // ---- exp + row sum (same reduction path)
    float s4[4] = {0.f, 0.f, 0.f, 0.f};
#pragma unroll
    for (int i = 0; i < 16; i++) {
#pragma unroll
        for (int r = 0; r < 4; r++) {
            float e = __expf(s[i][r] - mrow[r]);
            s[i][r] = e;
            s4[r] += e;
        }
    }
#pragma unroll
    for (int r = 0; r < 4; r++) {
#pragma unroll
        for (int msk = 8; msk >= 1; msk >>= 1) s4[r] += __shfl_xor(s4[r], msk, 64);
    }
    if (l15 == 0) {
#pragma unroll
        for (int r = 0; r < 4; r++) red[1][quad * 4 + r][wave] = s4[r];
    }
    __syncthreads();
    float inv[4];
#pragma unroll
    for (int r = 0; r < 4; r++) {
        float4 rr = *(const float4*)&red[1][quad * 4 + r][0];
        inv[r] = 1.0f / (rr.x + rr.y + rr.z + rr.w);
    }

    // ---- normalize: fp32 W straight to global (nontemporal), bf16 copy to LDS
    size_t wbase = (((size_t)b * NHEAD + h) * SEQ + rt * 16) * SEQ;
#pragma unroll
    for (int i = 0; i < 16; i++) {
        int col = (wave * 16 + i) * 16 + l15;
#pragma unroll
        for (int r = 0; r < 4; r++) {
            float w = s[i][r] * inv[r];
            int row = quad * 4 + r;
            __builtin_nontemporal_store(w, &Wout[wbase + (size_t)row * SEQ + col]);
            Sb[sbidx(row, col)] = (__bf16)w;
        }
    }
    __syncthreads();

    // ---- PV: ctx(16x64) = W(16x1024) @ v(1024x64); wave owns 16 d-cols
    floatx4 acc = {0.f, 0.f, 0.f, 0.f};
    const __bf16* vbase = vT + (((size_t)b * NHEAD + h) * DH + wave * 16 + l15) * SEQ;
#pragma unroll
    for (int c = 0; c < 32; c++) {
        int k0 = c * 32 + quad * 8;
        bf16x8 af = *(const bf16x8*)&Sb[sbidx(l15, k0)];
        bf16x8 bv = *(const bf16x8*)(vbase + k0);
        acc = MFMA_BF16(af, bv, acc);
    }
#pragma unroll
    for (int r = 0; r < 4; r++)
        ctx[((size_t)b * SEQ + rt * 16 + quad * 4 + r) * H + h * DH + wave * 16 + l15] =
            (__bf16)acc[r];
}

// ---------------------------------------------------------------- launch
extern "C" void kernel_launch(void* const* d_in, const int* in_sizes, int n_in,
                              void* d_out, int out_size, void* d_ws, size_t ws_size,
                              hipStream_t stream) {
    const float* x   = (const float*)d_in[0];
    const float* wq  = (const float*)d_in[1];
    const float* bq  = (const float*)d_in[2];
    const float* wk  = (const float*)d_in[3];
    const float* bk  = (const float*)d_in[4];
    const float* wv  = (const float*)d_in[5];
    const float* bv  = (const float*)d_in[6];
    const float* wo  = (const float*)d_in[7];
    const float* bo  = (const float*)d_in[8];
    const float* w1  = (const float*)d_in[9];
    const float* b1  = (const float*)d_in[10];
    const float* w2  = (const float*)d_in[11];
    const float* b2  = (const float*)d_in[12];
    const float* g1  = (const float*)d_in[13];
    const float* be1 = (const float*)d_in[14];
    const float* g2  = (const float*)d_in[15];
    const float* be2 = (const float*)d_in[16];

    char* ws = (char*)d_ws;
    const size_t SZB = (size_t)NTOK * H * 2;           // 12582912
    __bf16* x1b  = (__bf16*)(ws);
    __bf16* qkvb = (__bf16*)(ws + SZB);                // (8192, 2304) spans 3*SZB
    __bf16* vTb  = (__bf16*)(ws + 4 * SZB);
    __bf16* ctxb = (__bf16*)(ws + 5 * SZB);
    __bf16* x2b  = (__bf16*)(ws + 6 * SZB);
    __bf16* hb   = (__bf16*)(ws + 7 * SZB);            // 8192*3072*2
    size_t off = 7 * SZB + (size_t)NTOK * FFD * 2;
    float* xattn = (float*)(ws + off); off += (size_t)NTOK * H * 4;
    __bf16* wqkvT = (__bf16*)(ws + off); off += (size_t)3 * H * H * 2;  // (2304,768)
    __bf16* woT  = (__bf16*)(ws + off); off += (size_t)H * H * 2;
    __bf16* w1T  = (__bf16*)(ws + off); off += (size_t)H * FFD * 2;
    __bf16* w2T  = (__bf16*)(ws + off); off += (size_t)FFD * H * 2;
    float* bqkv  = (float*)(ws + off); off += (size_t)3 * H * 4;

    float* outx = (float*)d_out;
    float* outw = (float*)d_out + (size_t)NTOK * H;

    // fused prologue: all weight transposes + bias concat + LN1
    prep_kernel<<<8969, 256, 0, stream>>>(wq, wk, wv, wo, w1, w2, bq, bk, bv,
                                          wqkvT, woT, w1T, w2T, bqkv,
                                          x, g1, be1, x1b);

    // fused QKV projection: (8192,768) @ (2304,768)^T -> (8192,2304)
    gemm_kernel<false, false, true><<<dim3(QKVS / 128, NTOK / 128), 256, 0, stream>>>(
        x1b, wqkvT, bqkv, nullptr, qkvb, nullptr, QKVS, H);

    // v -> vT (b,h,d,n)
    vtrans_kernel<<<dim3(16, NHEAD, BATCH), dim3(64, 4), 0, stream>>>(qkvb, vTb);

    // attention (writes softmax weights to d_out and ctx to ws)
    attn_kernel<<<dim3(64, NHEAD, BATCH), 256, 0, stream>>>(qkvb, vTb, outw, ctxb);

    // out projection + residual(x) -> xattn fp32
    gemm_kernel<false, true, false><<<dim3(H / 128, NTOK / 128), 256, 0, stream>>>(
        ctxb, woT, bo, x, nullptr, xattn, H, H);

    // LN2
    ln_kernel<<<NTOK / 4, 256, 0, stream>>>(xattn, g2, be2, x2b);

    // FFN1 + exact GELU (A&S erf)
    gemm_kernel<true, false, true><<<dim3(FFD / 128, NTOK / 128), 256, 0, stream>>>(
        x2b, w1T, b1, nullptr, hb, nullptr, FFD, H);

    // FFN2 + residual(xattn) -> d_out[0:6291456]
    gemm_kernel<false, true, false><<<dim3(H / 128, NTOK / 128), 256, 0, stream>>>(
        hb, w2T, b2, xattn, nullptr, outx, H, FFD);
}

// Round 4
// 825.289 us; speedup vs baseline: 1.3036x; 1.0315x over previous
//
#include <hip/hip_runtime.h>
#include <cstdint>
#include <cstddef>

#define H 768
#define NHEAD 12
#define DH 64
#define FFD 3072
#define BATCH 8
#define SEQ 1024
#define NTOK (BATCH*SEQ)   // 8192
#define QKVS 2304          // fused qkv row stride

typedef __bf16 bf16x8 __attribute__((ext_vector_type(8)));
typedef float  floatx4 __attribute__((ext_vector_type(4)));

#define MFMA_BF16(a,b,c) __builtin_amdgcn_mfma_f32_16x16x32_bf16((a),(b),(c),0,0,0)

// async global->LDS, 16B per lane; dest must be wave-uniform base (lane*16 auto)
__device__ __forceinline__ void gload16(const void* g, void* l) {
    __builtin_amdgcn_global_load_lds((const __attribute__((address_space(1))) void*)g,
                                     (__attribute__((address_space(3))) void*)l,
                                     16, 0, 0);
}

// exact-GELU via A&S 7.1.26 erf (abs err <= 1.5e-7, ~1000x below bf16 noise)
__device__ __forceinline__ float gelu_erf(float x) {
    float z = fabsf(x) * 0.70710678118654752f;
    float t = __builtin_amdgcn_rcpf(1.0f + 0.3275911f * z);
    float poly = t * (0.254829592f +
               t * (-0.284496736f +
               t * (1.421413741f +
               t * (-1.453152027f +
               t * 1.061405429f))));
    float e = __expf(-z * z);
    float erfv = 1.0f - poly * e;
    erfv = copysignf(erfv, x);
    return 0.5f * x * (1.0f + erfv);
}

// ---------------------------------------------------------------- fused prologue
// blocks [0,6912): weight fp32(K,N) -> bf16 T(N,K) in 32x32 tiles
//   [0,576) wq  [576,1152) wk  [1152,1728) wv  -> wqkvT (stacked)
//   [1728,2304) wo -> woT
//   [2304,4608) w1 (gx=96) -> w1T
//   [4608,6912) w2 (gx=24, K=3072) -> w2T
// blocks [6912,6921): bias concat bq|bk|bv -> bqkv (2304 floats)
// blocks [6921,8969): LayerNorm1, 4 rows/block
__global__ __launch_bounds__(256) void prep_kernel(
    const float* __restrict__ wq, const float* __restrict__ wk,
    const float* __restrict__ wv, const float* __restrict__ wo,
    const float* __restrict__ w1, const float* __restrict__ w2,
    const float* __restrict__ bq, const float* __restrict__ bk,
    const float* __restrict__ bv,
    __bf16* __restrict__ wqkvT, __bf16* __restrict__ woT,
    __bf16* __restrict__ w1T, __bf16* __restrict__ w2T,
    float* __restrict__ bqkv,
    const float* __restrict__ x, const float* __restrict__ g1,
    const float* __restrict__ be1, __bf16* __restrict__ x1b) {
    __shared__ float tile[32][33];
    int bid = blockIdx.x;
    int tid = threadIdx.x;
    if (bid < 6912) {
        const float* W; __bf16* T; int Kd, Nn, bx, by;
        if (bid < 1728) {
            int part = bid / 576;          // 0 wq, 1 wk, 2 wv
            int rem = bid - part * 576;
            W = part == 0 ? wq : (part == 1 ? wk : wv);
            T = wqkvT + (size_t)part * H * H;
            Kd = H; Nn = H; bx = rem % 24; by = rem / 24;
        } else if (bid < 2304) {
            int rem = bid - 1728;
            W = wo; T = woT; Kd = H; Nn = H; bx = rem % 24; by = rem / 24;
        } else if (bid < 4608) {
            int rem = bid - 2304;
            W = w1; T = w1T; Kd = H; Nn = FFD; bx = rem % 96; by = rem / 96;
        } else {
            int rem = bid - 4608;
            W = w2; T = w2T; Kd = FFD; Nn = H; bx = rem % 24; by = rem / 24;
        }
        int tx = tid & 31, ty = tid >> 5;
        int n0 = bx * 32, k0 = by * 32;
#pragma unroll
        for (int i = 0; i < 32; i += 8)
            tile[ty + i][tx] = W[(size_t)(k0 + ty + i) * Nn + n0 + tx];
        __syncthreads();
#pragma unroll
        for (int i = 0; i < 32; i += 8)
            T[(size_t)(n0 + ty + i) * Kd + k0 + tx] = (__bf16)tile[tx][ty + i];
    } else if (bid < 6921) {
        int i = (bid - 6912) * 256 + tid;   // 2304 exact
        float v = i < H ? bq[i] : (i < 2 * H ? bk[i - H] : bv[i - 2 * H]);
        bqkv[i] = v;
    } else {
        int row  = (bid - 6921) * 4 + (tid >> 6);
        int lane = tid & 63;
        const float* xr = x + (size_t)row * H;
        float v[12];
        float s = 0.f;
#pragma unroll
        for (int i = 0; i < 12; i++) { v[i] = xr[lane + i * 64]; s += v[i]; }
#pragma unroll
        for (int m = 32; m >= 1; m >>= 1) s += __shfl_xor(s, m, 64);
        float mu = s * (1.0f / H);
        float q = 0.f;
#pragma unroll
        for (int i = 0; i < 12; i++) { float d = v[i] - mu; q += d * d; }
#pragma unroll
        for (int m = 32; m >= 1; m >>= 1) q += __shfl_xor(q, m, 64);
        float rstd = rsqrtf(q * (1.0f / H) + 1e-6f);
        __bf16* orow = x1b + (size_t)row * H;
#pragma unroll
        for (int i = 0; i < 12; i++) {
            int c = lane + i * 64;
            orow[c] = (__bf16)((v[i] - mu) * rstd * g1[c] + be1[c]);
        }
    }
}

// ---------------------------------------------------------------- LayerNorm (LN2)
__global__ __launch_bounds__(256) void ln_kernel(const float* __restrict__ x,
                                                 const float* __restrict__ g,
                                                 const float* __restrict__ be,
                                                 __bf16* __restrict__ out) {
    int row  = blockIdx.x * 4 + (threadIdx.x >> 6);
    int lane = threadIdx.x & 63;
    const float* xr = x + (size_t)row * H;
    float v[12];
    float s = 0.f;
#pragma unroll
    for (int i = 0; i < 12; i++) { v[i] = xr[lane + i * 64]; s += v[i]; }
#pragma unroll
    for (int m = 32; m >= 1; m >>= 1) s += __shfl_xor(s, m, 64);
    float mu = s * (1.0f / H);
    float q = 0.f;
#pragma unroll
    for (int i = 0; i < 12; i++) { float d = v[i] - mu; q += d * d; }
#pragma unroll
    for (int m = 32; m >= 1; m >>= 1) q += __shfl_xor(q, m, 64);
    float rstd = rsqrtf(q * (1.0f / H) + 1e-6f);
    __bf16* orow = out + (size_t)row * H;
#pragma unroll
    for (int i = 0; i < 12; i++) {
        int c = lane + i * 64;
        orow[c] = (__bf16)((v[i] - mu) * rstd * g[c] + be[c]);
    }
}

// --------------------------------- v (from qkv, stride 2304) -> vT (b,h,64,1024)
__global__ __launch_bounds__(256) void vtrans_kernel(const __bf16* __restrict__ qkv,
                                                     __bf16* __restrict__ vT) {
    __shared__ __bf16 tile[64][65];
    int b = blockIdx.z, h = blockIdx.y, n0 = blockIdx.x * 64;
    int tx = threadIdx.x, ty = threadIdx.y;
#pragma unroll
    for (int r = ty; r < 64; r += 4)
        tile[r][tx] = qkv[((size_t)b * SEQ + n0 + r) * QKVS + 2 * H + h * DH + tx];
    __syncthreads();
#pragma unroll
    for (int c = ty; c < 64; c += 4)
        vT[(((size_t)b * NHEAD + h) * DH + c) * SEQ + n0 + tx] = tile[tx][c];
}

// ---------------------------------------------------------------- GEMM
// C(M,Nn) = A(M,K)bf16 @ Bt(Nn,K)bf16^T + bias ; optional erf-GELU, fp32 residual
// 128x128 tile, BK=64, 4 waves 2x2, each wave 64x64; 32 MFMA 16x16x32 per K-step.
// Staging via global_load_lds width=16: tile = 16 chunks of 8 rows (1024B);
// wave w stages chunks 4w..4w+3. LDS kept LINEAR; bank-conflict-free reads via
// XOR swizzle applied on BOTH the global source col (write side) and the
// ds_read col (read side): col16 ^= row&7 (involution within 8-row stripes).
template<bool GELU, bool HAS_RES, bool OUT_BF16>
__global__ __launch_bounds__(256) void gemm_kernel(const __bf16* __restrict__ A,
                                                   const __bf16* __restrict__ Bt,
                                                   const float* __restrict__ bias,
                                                   const float* __restrict__ res,
                                                   __bf16* __restrict__ obf,
                                                   float* __restrict__ ofp,
                                                   int Nn, int K) {
    __shared__ __bf16 As[128 * 64];
    __shared__ __bf16 Bs[128 * 64];
    int tid = threadIdx.x;
    int wave = tid >> 6, lane = tid & 63;
    int wr = wave >> 1, wc = wave & 1;
    int l15 = lane & 15, quad = lane >> 4;

    floatx4 acc[4][4];
    floatx4 zero = {0.f, 0.f, 0.f, 0.f};
#pragma unroll
    for (int i = 0; i < 4; i++)
#pragma unroll
        for (int j = 0; j < 4; j++) acc[i][j] = zero;

    // staging addressing: chunk = wave*4+cc; row-in-chunk = lane>>3;
    // source col pre-swizzled so that LDS[row][b] = G[row][b ^ ((row&7)<<4)]
    int lrow = lane >> 3;                      // 0..7 (== row&7 within chunk)
    int lcol = ((lane & 7) ^ lrow) * 8;        // swizzled source col (bf16 elems)
    const __bf16* Agc[4];
    const __bf16* Bgc[4];
    __bf16* AsDc[4];
    __bf16* BsDc[4];
#pragma unroll
    for (int cc = 0; cc < 4; cc++) {
        int chunk = wave * 4 + cc;
        int row = chunk * 8 + lrow;
        Agc[cc] = A + (size_t)(blockIdx.y * 128 + row) * K + lcol;
        Bgc[cc] = Bt + (size_t)(blockIdx.x * 128 + row) * K + lcol;
        AsDc[cc] = &As[chunk * 512];
        BsDc[cc] = &Bs[chunk * 512];
    }

    for (int k0 = 0; k0 < K; k0 += 64) {
#pragma unroll
        for (int cc = 0; cc < 4; cc++) {
            gload16(Agc[cc] + k0, AsDc[cc]);
            gload16(Bgc[cc] + k0, BsDc[cc]);
        }
        __syncthreads();              // drains vmcnt; all 32KB staged
#pragma unroll
        for (int kk = 0; kk < 2; kk++) {
            int c16 = (kk * 4 + quad) ^ (l15 & 7);   // swizzled read col
            bf16x8 af[4], bfv[4];
#pragma unroll
            for (int i = 0; i < 4; i++)
                af[i] = *(const bf16x8*)&As[(wr * 64 + i * 16 + l15) * 64 + c16 * 8];
#pragma unroll
            for (int j = 0; j < 4; j++)
                bfv[j] = *(const bf16x8*)&Bs[(wc * 64 + j * 16 + l15) * 64 + c16 * 8];
#pragma unroll
            for (int i = 0; i < 4; i++)
#pragma unroll
                for (int j = 0; j < 4; j++)
                    acc[i][j] = MFMA_BF16(af[i], bfv[j], acc[i][j]);
        }
        __syncthreads();
    }

#pragma unroll
    for (int i = 0; i < 4; i++) {
        int row = blockIdx.y * 128 + wr * 64 + i * 16 + quad * 4;
#pragma unroll
        for (int j = 0; j < 4; j++) {
            int col = blockIdx.x * 128 + wc * 64 + j * 16 + l15;
            float bsv = bias[col];
#pragma unroll
            for (int r = 0; r < 4; r++) {
                float vv = acc[i][j][r] + bsv;
                if (GELU) vv = gelu_erf(vv);
                if (HAS_RES) vv += res[(size_t)(row + r) * Nn + col];
                if (OUT_BF16) obf[(size_t)(row + r) * Nn + col] = (__bf16)vv;
                else          ofp[(size_t)(row + r) * Nn + col] = vv;
            }
        }
    }
}

// ---------------------------------------------------------------- Attention
// Per block: 16 query rows of one (b,h). S held entirely in REGISTERS.
// XCD-locality remap: all 64 rt-blocks of one (b,h) land on ONE XCD so the
// 256KB K/V slice stays resident in that XCD's private L2 (dispatch is
// round-robin on linear block id; XCD = linear & 7).
__device__ __forceinline__ int sbidx(int row, int col) {
    return row * 1024 + (col ^ ((row & 7) << 3));
}

__global__ __launch_bounds__(256, 4) void attn_kernel(const __bf16* __restrict__ qkv,
                                                      const __bf16* __restrict__ vT,
                                                      float* __restrict__ Wout,
                                                      __bf16* __restrict__ ctx) {
    __shared__ __bf16 Sb[16 * 1024];               // 32 KB, swizzled bf16 weights
    __shared__ __align__(16) float red[2][16][4];  // [max/sum][row][wave]
    int tid = threadIdx.x;
    int wave = tid >> 6, lane = tid & 63, l15 = lane & 15, quad = lane >> 4;

    // bijective remap: XCD (linear&7) owns whole (b,h) groups
    int linear = blockIdx.x + 64 * (blockIdx.y + 12 * blockIdx.z);
    int xcd = linear & 7;
    int j   = linear >> 3;                 // 0..767
    int bh  = xcd + 8 * (j >> 6);          // 0..95
    int rt  = j & 63;
    int h = bh % NHEAD, b = bh / NHEAD;

    const size_t tokbase = (size_t)b * SEQ * QKVS + h * DH;
    const float scale = 0.03608439182435161f;   // 1/sqrt(768)

    // q fragments (16 rows x 64 k) in regs, shared by all column tiles
    const __bf16* qrow = qkv + tokbase + (size_t)(rt * 16 + l15) * QKVS;
    bf16x8 qf0 = *(const bf16x8*)(qrow + quad * 8);
    bf16x8 qf1 = *(const bf16x8*)(qrow + 32 + quad * 8);

    // ---- QK^T: wave owns 16 contiguous column tiles; S stays in regs
    floatx4 s[16];
    const __bf16* kbase = qkv + tokbase + H;       // k at +768 within row
#pragma unroll
    for (int i = 0; i < 16; i++) {
        int ct = wave * 16 + i;
        const __bf16* krow = kbase + (size_t)(ct * 16 + l15) * QKVS;
        bf16x8 kf0 = *(const bf16x8*)(krow + quad * 8);
        bf16x8 kf1 = *(const bf16x8*)(krow + 32 + quad * 8);
        floatx4 a = {0.f, 0.f, 0.f, 0.f};
        a = MFMA_BF16(qf0, kf0, a);
        a = MFMA_BF16(qf1, kf1, a);
#pragma unroll
        for (int r = 0; r < 4; r++) s[i][r] = a[r] * scale;
    }

    // ---- row max: local over 16 tiles, shfl over 16 lanes, LDS over 4 waves
    float m4[4];
#pragma unroll
    for (int r = 0; r < 4; r++) {
        float m = s[0][r];
#pragma unroll
        for (int i = 1; i < 16; i++) m = fmaxf(m, s[i][r]);
#pragma unroll
        for (int msk = 8; msk >= 1; msk >>= 1) m = fmaxf(m, __shfl_xor(m, msk, 64));
        m4[r] = m;
    }
    if (l15 == 0) {
#pragma unroll
        for (int r = 0; r < 4; r++) red[0][quad * 4 + r][wave] = m4[r];
    }
    __syncthreads();
    float mrow[4];
#pragma unroll
    for (int r = 0; r < 4; r++) {
        float4 rr = *(const float4*)&red[0][quad * 4 + r][0];
        mrow[r] = fmaxf(fmaxf(rr.x, rr.y), fmaxf(rr.z, rr.w));
    }

    // ---- exp + row sum (same reduction path)
    float s4[4] = {0.f, 0.f, 0.f, 0.f};
#pragma unroll
    for (int i = 0; i < 16; i++) {
#pragma unroll
        for (int r = 0; r < 4; r++) {
            float e = __expf(s[i][r] - mrow[r]);
            s[i][r] = e;
            s4[r] += e;
        }
    }
#pragma unroll
    for (int r = 0; r < 4; r++) {
#pragma unroll
        for (int msk = 8; msk >= 1; msk >>= 1) s4[r] += __shfl_xor(s4[r], msk, 64);
    }
    if (l15 == 0) {
#pragma unroll
        for (int r = 0; r < 4; r++) red[1][quad * 4 + r][wave] = s4[r];
    }
    __syncthreads();
    float inv[4];
#pragma unroll
    for (int r = 0; r < 4; r++) {
        float4 rr = *(const float4*)&red[1][quad * 4 + r][0];
        inv[r] = 1.0f / (rr.x + rr.y + rr.z + rr.w);
    }

    // ---- normalize: fp32 W straight to global (nontemporal), bf16 copy to LDS
    size_t wbase = (((size_t)b * NHEAD + h) * SEQ + rt * 16) * SEQ;
#pragma unroll
    for (int i = 0; i < 16; i++) {
        int col = (wave * 16 + i) * 16 + l15;
#pragma unroll
        for (int r = 0; r < 4; r++) {
            float w = s[i][r] * inv[r];
            int row = quad * 4 + r;
            __builtin_nontemporal_store(w, &Wout[wbase + (size_t)row * SEQ + col]);
            Sb[sbidx(row, col)] = (__bf16)w;
        }
    }
    __syncthreads();

    // ---- PV: ctx(16x64) = W(16x1024) @ v(1024x64); wave owns 16 d-cols
    floatx4 acc = {0.f, 0.f, 0.f, 0.f};
    const __bf16* vbase = vT + (((size_t)b * NHEAD + h) * DH + wave * 16 + l15) * SEQ;
#pragma unroll
    for (int c = 0; c < 32; c++) {
        int k0 = c * 32 + quad * 8;
        bf16x8 af = *(const bf16x8*)&Sb[sbidx(l15, k0)];
        bf16x8 bv = *(const bf16x8*)(vbase + k0);
        acc = MFMA_BF16(af, bv, acc);
    }
#pragma unroll
    for (int r = 0; r < 4; r++)
        ctx[((size_t)b * SEQ + rt * 16 + quad * 4 + r) * H + h * DH + wave * 16 + l15] =
            (__bf16)acc[r];
}

// ---------------------------------------------------------------- launch
extern "C" void kernel_launch(void* const* d_in, const int* in_sizes, int n_in,
                              void* d_out, int out_size, void* d_ws, size_t ws_size,
                              hipStream_t stream) {
    const float* x   = (const float*)d_in[0];
    const float* wq  = (const float*)d_in[1];
    const float* bq  = (const float*)d_in[2];
    const float* wk  = (const float*)d_in[3];
    const float* bk  = (const float*)d_in[4];
    const float* wv  = (const float*)d_in[5];
    const float* bv  = (const float*)d_in[6];
    const float* wo  = (const float*)d_in[7];
    const float* bo  = (const float*)d_in[8];
    const float* w1  = (const float*)d_in[9];
    const float* b1  = (const float*)d_in[10];
    const float* w2  = (const float*)d_in[11];
    const float* b2  = (const float*)d_in[12];
    const float* g1  = (const float*)d_in[13];
    const float* be1 = (const float*)d_in[14];
    const float* g2  = (const float*)d_in[15];
    const float* be2 = (const float*)d_in[16];

    char* ws = (char*)d_ws;
    const size_t SZB = (size_t)NTOK * H * 2;           // 12582912
    __bf16* x1b  = (__bf16*)(ws);
    __bf16* qkvb = (__bf16*)(ws + SZB);                // (8192, 2304) spans 3*SZB
    __bf16* vTb  = (__bf16*)(ws + 4 * SZB);
    __bf16* ctxb = (__bf16*)(ws + 5 * SZB);
    __bf16* x2b  = (__bf16*)(ws + 6 * SZB);
    __bf16* hb   = (__bf16*)(ws + 7 * SZB);            // 8192*3072*2
    size_t off = 7 * SZB + (size_t)NTOK * FFD * 2;
    float* xattn = (float*)(ws + off); off += (size_t)NTOK * H * 4;
    __bf16* wqkvT = (__bf16*)(ws + off); off += (size_t)3 * H * H * 2;  // (2304,768)
    __bf16* woT  = (__bf16*)(ws + off); off += (size_t)H * H * 2;
    __bf16* w1T  = (__bf16*)(ws + off); off += (size_t)H * FFD * 2;
    __bf16* w2T  = (__bf16*)(ws + off); off += (size_t)FFD * H * 2;
    float* bqkv  = (float*)(ws + off); off += (size_t)3 * H * 4;

    float* outx = (float*)d_out;
    float* outw = (float*)d_out + (size_t)NTOK * H;

    // fused prologue: all weight transposes + bias concat + LN1
    prep_kernel<<<8969, 256, 0, stream>>>(wq, wk, wv, wo, w1, w2, bq, bk, bv,
                                          wqkvT, woT, w1T, w2T, bqkv,
                                          x, g1, be1, x1b);

    // fused QKV projection: (8192,768) @ (2304,768)^T -> (8192,2304)
    gemm_kernel<false, false, true><<<dim3(QKVS / 128, NTOK / 128), 256, 0, stream>>>(
        x1b, wqkvT, bqkv, nullptr, qkvb, nullptr, QKVS, H);

    // v -> vT (b,h,d,n)
    vtrans_kernel<<<dim3(16, NHEAD, BATCH), dim3(64, 4), 0, stream>>>(qkvb, vTb);

    // attention (writes softmax weights to d_out and ctx to ws)
    attn_kernel<<<dim3(64, NHEAD, BATCH), 256, 0, stream>>>(qkvb, vTb, outw, ctxb);

    // out projection + residual(x) -> xattn fp32
    gemm_kernel<false, true, false><<<dim3(H / 128, NTOK / 128), 256, 0, stream>>>(
        ctxb, woT, bo, x, nullptr, xattn, H, H);

    // LN2
    ln_kernel<<<NTOK / 4, 256, 0, stream>>>(xattn, g2, be2, x2b);

    // FFN1 + exact GELU (A&S erf)
    gemm_kernel<true, false, true><<<dim3(FFD / 128, NTOK / 128), 256, 0, stream>>>(
        x2b, w1T, b1, nullptr, hb, nullptr, FFD, H);

    // FFN2 + residual(xattn) -> d_out[0:6291456]
    gemm_kernel<false, true, false><<<dim3(H / 128, NTOK / 128), 256, 0, stream>>>(
        hb, w2T, b2, xattn, nullptr, outx, H, FFD);
}

// Round 5
// 815.942 us; speedup vs baseline: 1.3185x; 1.0115x over previous
//
#include <hip/hip_runtime.h>
#include <cstdint>
#include <cstddef>

#define H 768
#define NHEAD 12
#define DH 64
#define FFD 3072
#define BATCH 8
#define SEQ 1024
#define NTOK (BATCH*SEQ)   // 8192
#define QKVS 2304          // fused qkv row stride

typedef __bf16 bf16x8 __attribute__((ext_vector_type(8)));
typedef float  floatx4 __attribute__((ext_vector_type(4)));

#define MFMA_BF16(a,b,c) __builtin_amdgcn_mfma_f32_16x16x32_bf16((a),(b),(c),0,0,0)

// async global->LDS, 16B per lane; dest must be wave-uniform base (lane*16 auto)
__device__ __forceinline__ void gload16(const void* g, void* l) {
    __builtin_amdgcn_global_load_lds((const __attribute__((address_space(1))) void*)g,
                                     (__attribute__((address_space(3))) void*)l,
                                     16, 0, 0);
}

// exact-GELU via A&S 7.1.26 erf (abs err <= 1.5e-7, ~1000x below bf16 noise)
__device__ __forceinline__ float gelu_erf(float x) {
    float z = fabsf(x) * 0.70710678118654752f;
    float t = __builtin_amdgcn_rcpf(1.0f + 0.3275911f * z);
    float poly = t * (0.254829592f +
               t * (-0.284496736f +
               t * (1.421413741f +
               t * (-1.453152027f +
               t * 1.061405429f))));
    float e = __expf(-z * z);
    float erfv = 1.0f - poly * e;
    erfv = copysignf(erfv, x);
    return 0.5f * x * (1.0f + erfv);
}

// ---------------------------------------------------------------- fused prologue
// blocks [0,6912): weight fp32(K,N) -> bf16 T(N,K) in 32x32 tiles
// blocks [6912,6921): bias concat bq|bk|bv -> bqkv (2304 floats)
// blocks [6921,8969): LayerNorm1, 4 rows/block
__global__ __launch_bounds__(256) void prep_kernel(
    const float* __restrict__ wq, const float* __restrict__ wk,
    const float* __restrict__ wv, const float* __restrict__ wo,
    const float* __restrict__ w1, const float* __restrict__ w2,
    const float* __restrict__ bq, const float* __restrict__ bk,
    const float* __restrict__ bv,
    __bf16* __restrict__ wqkvT, __bf16* __restrict__ woT,
    __bf16* __restrict__ w1T, __bf16* __restrict__ w2T,
    float* __restrict__ bqkv,
    const float* __restrict__ x, const float* __restrict__ g1,
    const float* __restrict__ be1, __bf16* __restrict__ x1b) {
    __shared__ float tile[32][33];
    int bid = blockIdx.x;
    int tid = threadIdx.x;
    if (bid < 6912) {
        const float* W; __bf16* T; int Kd, Nn, bx, by;
        if (bid < 1728) {
            int part = bid / 576;          // 0 wq, 1 wk, 2 wv
            int rem = bid - part * 576;
            W = part == 0 ? wq : (part == 1 ? wk : wv);
            T = wqkvT + (size_t)part * H * H;
            Kd = H; Nn = H; bx = rem % 24; by = rem / 24;
        } else if (bid < 2304) {
            int rem = bid - 1728;
            W = wo; T = woT; Kd = H; Nn = H; bx = rem % 24; by = rem / 24;
        } else if (bid < 4608) {
            int rem = bid - 2304;
            W = w1; T = w1T; Kd = H; Nn = FFD; bx = rem % 96; by = rem / 96;
        } else {
            int rem = bid - 4608;
            W = w2; T = w2T; Kd = FFD; Nn = H; bx = rem % 24; by = rem / 24;
        }
        int tx = tid & 31, ty = tid >> 5;
        int n0 = bx * 32, k0 = by * 32;
#pragma unroll
        for (int i = 0; i < 32; i += 8)
            tile[ty + i][tx] = W[(size_t)(k0 + ty + i) * Nn + n0 + tx];
        __syncthreads();
#pragma unroll
        for (int i = 0; i < 32; i += 8)
            T[(size_t)(n0 + ty + i) * Kd + k0 + tx] = (__bf16)tile[tx][ty + i];
    } else if (bid < 6921) {
        int i = (bid - 6912) * 256 + tid;   // 2304 exact
        float v = i < H ? bq[i] : (i < 2 * H ? bk[i - H] : bv[i - 2 * H]);
        bqkv[i] = v;
    } else {
        int row  = (bid - 6921) * 4 + (tid >> 6);
        int lane = tid & 63;
        const float* xr = x + (size_t)row * H;
        float v[12];
        float s = 0.f;
#pragma unroll
        for (int i = 0; i < 12; i++) { v[i] = xr[lane + i * 64]; s += v[i]; }
#pragma unroll
        for (int m = 32; m >= 1; m >>= 1) s += __shfl_xor(s, m, 64);
        float mu = s * (1.0f / H);
        float q = 0.f;
#pragma unroll
        for (int i = 0; i < 12; i++) { float d = v[i] - mu; q += d * d; }
#pragma unroll
        for (int m = 32; m >= 1; m >>= 1) q += __shfl_xor(q, m, 64);
        float rstd = rsqrtf(q * (1.0f / H) + 1e-6f);
        __bf16* orow = x1b + (size_t)row * H;
#pragma unroll
        for (int i = 0; i < 12; i++) {
            int c = lane + i * 64;
            orow[c] = (__bf16)((v[i] - mu) * rstd * g1[c] + be1[c]);
        }
    }
}

// ---------------------------------------------------------------- LayerNorm (LN2)
__global__ __launch_bounds__(256) void ln_kernel(const float* __restrict__ x,
                                                 const float* __restrict__ g,
                                                 const float* __restrict__ be,
                                                 __bf16* __restrict__ out) {
    int row  = blockIdx.x * 4 + (threadIdx.x >> 6);
    int lane = threadIdx.x & 63;
    const float* xr = x + (size_t)row * H;
    float v[12];
    float s = 0.f;
#pragma unroll
    for (int i = 0; i < 12; i++) { v[i] = xr[lane + i * 64]; s += v[i]; }
#pragma unroll
    for (int m = 32; m >= 1; m >>= 1) s += __shfl_xor(s, m, 64);
    float mu = s * (1.0f / H);
    float q = 0.f;
#pragma unroll
    for (int i = 0; i < 12; i++) { float d = v[i] - mu; q += d * d; }
#pragma unroll
    for (int m = 32; m >= 1; m >>= 1) q += __shfl_xor(q, m, 64);
    float rstd = rsqrtf(q * (1.0f / H) + 1e-6f);
    __bf16* orow = out + (size_t)row * H;
#pragma unroll
    for (int i = 0; i < 12; i++) {
        int c = lane + i * 64;
        orow[c] = (__bf16)((v[i] - mu) * rstd * g[c] + be[c]);
    }
}

// ---------------------------------------------------------------- GEMM
// C(M,Nn) = A(M,K)bf16 @ Bt(Nn,K)bf16^T + bias ; optional erf-GELU, fp32 residual
// TM=128: 128x128 tile, 4 waves 2x2 (wave 64x64, acc 4x4)
// TM=64 :  64x128 tile, 4 waves 1x4 (wave 64x32, acc 4x2) — for N=768 GEMMs,
//          doubles grid to 768 blocks so all CUs stay balanced/resident.
// Staging via global_load_lds width=16, LDS linear, XOR swizzle on BOTH sides
// (source col and read col: col16 ^= row&7 within 8-row stripes). BK=64.
// VWRITE: for QKV fusion — column-blocks >=12 (the V range) write the
// accumulator TRANSPOSED into vT(b,h,d,n) instead of into the qkv buffer.
template<bool GELU, bool HAS_RES, bool OUT_BF16, int TM, bool VWRITE, bool NT>
__global__ __launch_bounds__(256) void gemm_kernel(const __bf16* __restrict__ A,
                                                   const __bf16* __restrict__ Bt,
                                                   const float* __restrict__ bias,
                                                   const float* __restrict__ res,
                                                   __bf16* __restrict__ obf,
                                                   float* __restrict__ ofp,
                                                   __bf16* __restrict__ vT,
                                                   int Nn, int K) {
    __shared__ __bf16 As[TM * 64];
    __shared__ __bf16 Bs[128 * 64];
    int tid = threadIdx.x;
    int wave = tid >> 6, lane = tid & 63;
    int l15 = lane & 15, quad = lane >> 4;
    constexpr int NJ = (TM == 128) ? 4 : 2;
    int brow0 = (TM == 128) ? (wave >> 1) * 64 : 0;
    int bcol0 = (TM == 128) ? (wave & 1) * 64 : wave * 32;

    floatx4 acc[4][NJ];
    floatx4 zero = {0.f, 0.f, 0.f, 0.f};
#pragma unroll
    for (int i = 0; i < 4; i++)
#pragma unroll
        for (int j = 0; j < NJ; j++) acc[i][j] = zero;

    // staging: 1KB chunks of 8 rows; source col pre-swizzled so
    // LDS[row][b16] = G[row][b16 ^ (row&7)]
    int lrow = lane >> 3;                      // 0..7
    int lcol = ((lane & 7) ^ lrow) * 8;        // swizzled source col (bf16 elems)
    constexpr int ACH = TM / 32;               // A chunks per wave (4 or 2)
    const __bf16* Agc[ACH];
    const __bf16* Bgc[4];
    __bf16* AsDc[ACH];
    __bf16* BsDc[4];
#pragma unroll
    for (int cc = 0; cc < ACH; cc++) {
        int chunk = wave * ACH + cc;           // [0, TM/8)
        int row = chunk * 8 + lrow;
        Agc[cc] = A + (size_t)(blockIdx.y * TM + row) * K + lcol;
        AsDc[cc] = &As[chunk * 512];
    }
#pragma unroll
    for (int cc = 0; cc < 4; cc++) {
        int chunk = wave * 4 + cc;             // [0,16)
        int row = chunk * 8 + lrow;
        Bgc[cc] = Bt + (size_t)(blockIdx.x * 128 + row) * K + lcol;
        BsDc[cc] = &Bs[chunk * 512];
    }

    for (int k0 = 0; k0 < K; k0 += 64) {
#pragma unroll
        for (int cc = 0; cc < ACH; cc++) gload16(Agc[cc] + k0, AsDc[cc]);
#pragma unroll
        for (int cc = 0; cc < 4; cc++)   gload16(Bgc[cc] + k0, BsDc[cc]);
        __syncthreads();              // drains vmcnt; tile staged
#pragma unroll
        for (int kk = 0; kk < 2; kk++) {
            int c16 = (kk * 4 + quad) ^ (l15 & 7);   // swizzled read col
            bf16x8 af[4], bfv[NJ];
#pragma unroll
            for (int i = 0; i < 4; i++)
                af[i] = *(const bf16x8*)&As[(brow0 + i * 16 + l15) * 64 + c16 * 8];
#pragma unroll
            for (int j = 0; j < NJ; j++)
                bfv[j] = *(const bf16x8*)&Bs[(bcol0 + j * 16 + l15) * 64 + c16 * 8];
#pragma unroll
            for (int i = 0; i < 4; i++)
#pragma unroll
                for (int j = 0; j < NJ; j++)
                    acc[i][j] = MFMA_BF16(af[i], bfv[j], acc[i][j]);
        }
        __syncthreads();
    }

#pragma unroll
    for (int i = 0; i < 4; i++) {
        int row = blockIdx.y * TM + brow0 + i * 16 + quad * 4;
#pragma unroll
        for (int j = 0; j < NJ; j++) {
            int col = blockIdx.x * 128 + bcol0 + j * 16 + l15;
            float bsv = bias[col];
#pragma unroll
            for (int r = 0; r < 4; r++) {
                float vv = acc[i][j][r] + bsv;
                if (GELU) vv = gelu_erf(vv);
                if (HAS_RES) vv += res[(size_t)(row + r) * Nn + col];
                if (VWRITE && blockIdx.x >= 12) {
                    // V range: write transposed into vT(b,h,d,n)
                    int vcol = col - 2 * H;
                    int hh = vcol >> 6, dd = vcol & 63;
                    int rr = row + r;
                    int bb = rr >> 10, nn = rr & 1023;
                    vT[(((size_t)bb * NHEAD + hh) * DH + dd) * SEQ + nn] = (__bf16)vv;
                } else if (OUT_BF16) {
                    obf[(size_t)(row + r) * Nn + col] = (__bf16)vv;
                } else if (NT) {
                    __builtin_nontemporal_store(vv, &ofp[(size_t)(row + r) * Nn + col]);
                } else {
                    ofp[(size_t)(row + r) * Nn + col] = vv;
                }
            }
        }
    }
}

// ---------------------------------------------------------------- Attention
// Per block: 16 query rows of one (b,h). S held entirely in REGISTERS.
// XCD-locality remap: all 64 rt-blocks of one (b,h) land on ONE XCD.
__device__ __forceinline__ int sbidx(int row, int col) {
    return row * 1024 + (col ^ ((row & 7) << 3));
}

__global__ __launch_bounds__(256, 4) void attn_kernel(const __bf16* __restrict__ qkv,
                                                      const __bf16* __restrict__ vT,
                                                      float* __restrict__ Wout,
                                                      __bf16* __restrict__ ctx) {
    __shared__ __bf16 Sb[16 * 1024];               // 32 KB, swizzled bf16 weights
    __shared__ __align__(16) float red[2][16][4];  // [max/sum][row][wave]
    int tid = threadIdx.x;
    int wave = tid >> 6, lane = tid & 63, l15 = lane & 15, quad = lane >> 4;

    // bijective remap: XCD (linear&7) owns whole (b,h) groups
    int linear = blockIdx.x + 64 * (blockIdx.y + 12 * blockIdx.z);
    int xcd = linear & 7;
    int j   = linear >> 3;                 // 0..767
    int bh  = xcd + 8 * (j >> 6);          // 0..95
    int rt  = j & 63;
    int h = bh % NHEAD, b = bh / NHEAD;

    const size_t tokbase = (size_t)b * SEQ * QKVS + h * DH;
    const float scale = 0.03608439182435161f;   // 1/sqrt(768)

    // q fragments (16 rows x 64 k) in regs, shared by all column tiles
    const __bf16* qrow = qkv + tokbase + (size_t)(rt * 16 + l15) * QKVS;
    bf16x8 qf0 = *(const bf16x8*)(qrow + quad * 8);
    bf16x8 qf1 = *(const bf16x8*)(qrow + 32 + quad * 8);

    // ---- QK^T: wave owns 16 contiguous column tiles; S stays in regs
    floatx4 s[16];
    const __bf16* kbase = qkv + tokbase + H;       // k at +768 within row
#pragma unroll
    for (int i = 0; i < 16; i++) {
        int ct = wave * 16 + i;
        const __bf16* krow = kbase + (size_t)(ct * 16 + l15) * QKVS;
        bf16x8 kf0 = *(const bf16x8*)(krow + quad * 8);
        bf16x8 kf1 = *(const bf16x8*)(krow + 32 + quad * 8);
        floatx4 a = {0.f, 0.f, 0.f, 0.f};
        a = MFMA_BF16(qf0, kf0, a);
        a = MFMA_BF16(qf1, kf1, a);
#pragma unroll
        for (int r = 0; r < 4; r++) s[i][r] = a[r] * scale;
    }

    // ---- row max: local over 16 tiles, shfl over 16 lanes, LDS over 4 waves
    float m4[4];
#pragma unroll
    for (int r = 0; r < 4; r++) {
        float m = s[0][r];
#pragma unroll
        for (int i = 1; i < 16; i++) m = fmaxf(m, s[i][r]);
#pragma unroll
        for (int msk = 8; msk >= 1; msk >>= 1) m = fmaxf(m, __shfl_xor(m, msk, 64));
        m4[r] = m;
    }
    if (l15 == 0) {
#pragma unroll
        for (int r = 0; r < 4; r++) red[0][quad * 4 + r][wave] = m4[r];
    }
    __syncthreads();
    float mrow[4];
#pragma unroll
    for (int r = 0; r < 4; r++) {
        float4 rr = *(const float4*)&red[0][quad * 4 + r][0];
        mrow[r] = fmaxf(fmaxf(rr.x, rr.y), fmaxf(rr.z, rr.w));
    }

    // ---- exp + row sum (same reduction path)
    float s4[4] = {0.f, 0.f, 0.f, 0.f};
#pragma unroll
    for (int i = 0; i < 16; i++) {
#pragma unroll
        for (int r = 0; r < 4; r++) {
            float e = __expf(s[i][r] - mrow[r]);
            s[i][r] = e;
            s4[r] += e;
        }
    }
#pragma unroll
    for (int r = 0; r < 4; r++) {
#pragma unroll
        for (int msk = 8; msk >= 1; msk >>= 1) s4[r] += __shfl_xor(s4[r], msk, 64);
    }
    if (l15 == 0) {
#pragma unroll
        for (int r = 0; r < 4; r++) red[1][quad * 4 + r][wave] = s4[r];
    }
    __syncthreads();
    float inv[4];
#pragma unroll
    for (int r = 0; r < 4; r++) {
        float4 rr = *(const float4*)&red[1][quad * 4 + r][0];
        inv[r] = 1.0f / (rr.x + rr.y + rr.z + rr.w);
    }

    // ---- normalize: fp32 W straight to global (nontemporal), bf16 copy to LDS
    size_t wbase = (((size_t)b * NHEAD + h) * SEQ + rt * 16) * SEQ;
#pragma unroll
    for (int i = 0; i < 16; i++) {
        int col = (wave * 16 + i) * 16 + l15;
#pragma unroll
        for (int r = 0; r < 4; r++) {
            float w = s[i][r] * inv[r];
            int row = quad * 4 + r;
            __builtin_nontemporal_store(w, &Wout[wbase + (size_t)row * SEQ + col]);
            Sb[sbidx(row, col)] = (__bf16)w;
        }
    }
    __syncthreads();

    // ---- PV: ctx(16x64) = W(16x1024) @ v(1024x64); wave owns 16 d-cols
    floatx4 acc = {0.f, 0.f, 0.f, 0.f};
    const __bf16* vbase = vT + (((size_t)b * NHEAD + h) * DH + wave * 16 + l15) * SEQ;
#pragma unroll
    for (int c = 0; c < 32; c++) {
        int k0 = c * 32 + quad * 8;
        bf16x8 af = *(const bf16x8*)&Sb[sbidx(l15, k0)];
        bf16x8 bv = *(const bf16x8*)(vbase + k0);
        acc = MFMA_BF16(af, bv, acc);
    }
#pragma unroll
    for (int r = 0; r < 4; r++)
        ctx[((size_t)b * SEQ + rt * 16 + quad * 4 + r) * H + h * DH + wave * 16 + l15] =
            (__bf16)acc[r];
}

// ---------------------------------------------------------------- launch
extern "C" void kernel_launch(void* const* d_in, const int* in_sizes, int n_in,
                              void* d_out, int out_size, void* d_ws, size_t ws_size,
                              hipStream_t stream) {
    const float* x   = (const float*)d_in[0];
    const float* wq  = (const float*)d_in[1];
    const float* bq  = (const float*)d_in[2];
    const float* wk  = (const float*)d_in[3];
    const float* bk  = (const float*)d_in[4];
    const float* wv  = (const float*)d_in[5];
    const float* bv  = (const float*)d_in[6];
    const float* wo  = (const float*)d_in[7];
    const float* bo  = (const float*)d_in[8];
    const float* w1  = (const float*)d_in[9];
    const float* b1  = (const float*)d_in[10];
    const float* w2  = (const float*)d_in[11];
    const float* b2  = (const float*)d_in[12];
    const float* g1  = (const float*)d_in[13];
    const float* be1 = (const float*)d_in[14];
    const float* g2  = (const float*)d_in[15];
    const float* be2 = (const float*)d_in[16];

    char* ws = (char*)d_ws;
    const size_t SZB = (size_t)NTOK * H * 2;           // 12582912
    __bf16* x1b  = (__bf16*)(ws);
    __bf16* qkvb = (__bf16*)(ws + SZB);                // (8192, 2304) spans 3*SZB
    __bf16* vTb  = (__bf16*)(ws + 4 * SZB);
    __bf16* ctxb = (__bf16*)(ws + 5 * SZB);
    __bf16* x2b  = (__bf16*)(ws + 6 * SZB);
    __bf16* hb   = (__bf16*)(ws + 7 * SZB);            // 8192*3072*2
    size_t off = 7 * SZB + (size_t)NTOK * FFD * 2;
    float* xattn = (float*)(ws + off); off += (size_t)NTOK * H * 4;
    __bf16* wqkvT = (__bf16*)(ws + off); off += (size_t)3 * H * H * 2;  // (2304,768)
    __bf16* woT  = (__bf16*)(ws + off); off += (size_t)H * H * 2;
    __bf16* w1T  = (__bf16*)(ws + off); off += (size_t)H * FFD * 2;
    __bf16* w2T  = (__bf16*)(ws + off); off += (size_t)FFD * H * 2;
    float* bqkv  = (float*)(ws + off); off += (size_t)3 * H * 4;

    float* outx = (float*)d_out;
    float* outw = (float*)d_out + (size_t)NTOK * H;

    // fused prologue: all weight transposes + bias concat + LN1
    prep_kernel<<<8969, 256, 0, stream>>>(wq, wk, wv, wo, w1, w2, bq, bk, bv,
                                          wqkvT, woT, w1T, w2T, bqkv,
                                          x, g1, be1, x1b);

    // fused QKV projection; V columns written transposed straight into vT
    gemm_kernel<false, false, true, 128, true, false>
        <<<dim3(QKVS / 128, NTOK / 128), 256, 0, stream>>>(
        x1b, wqkvT, bqkv, nullptr, qkvb, nullptr, vTb, QKVS, H);

    // attention (writes softmax weights to d_out and ctx to ws)
    attn_kernel<<<dim3(64, NHEAD, BATCH), 256, 0, stream>>>(qkvb, vTb, outw, ctxb);

    // out projection + residual(x) -> xattn fp32 (64-row tiles, 768 blocks)
    gemm_kernel<false, true, false, 64, false, false>
        <<<dim3(H / 128, NTOK / 64), 256, 0, stream>>>(
        ctxb, woT, bo, x, nullptr, xattn, nullptr, H, H);

    // LN2
    ln_kernel<<<NTOK / 4, 256, 0, stream>>>(xattn, g2, be2, x2b);

    // FFN1 + exact GELU (A&S erf)
    gemm_kernel<true, false, true, 128, false, false>
        <<<dim3(FFD / 128, NTOK / 128), 256, 0, stream>>>(
        x2b, w1T, b1, nullptr, hb, nullptr, nullptr, FFD, H);

    // FFN2 + residual(xattn) -> d_out (64-row tiles, 768 blocks, nontemporal)
    gemm_kernel<false, true, false, 64, false, true>
        <<<dim3(H / 128, NTOK / 64), 256, 0, stream>>>(
        hb, w2T, b2, xattn, nullptr, outx, nullptr, H, FFD);
}